// Round 1
// baseline (4749.504 us; speedup 1.0000x reference)
//
#include <hip/hip_runtime.h>
#include <hip/hip_bf16.h>
#include <math.h>

// Problem constants
#define NTR   7680      // N*T
#define NJ    25
#define NKEEP 17
#define NDRP  8
#define NL    19        // 1 + 17 + 1
#define NROW  192000    // NT*J == N*J*T
#define NTT   120

__device__ __forceinline__ float gelu_exact(float v){
    return 0.5f * v * (1.0f + erff(v * 0.70710678118654752440f));
}

#define WAVE_RED(v) \
    v += __shfl_xor(v,32,64); v += __shfl_xor(v,16,64); v += __shfl_xor(v,8,64); \
    v += __shfl_xor(v,4,64);  v += __shfl_xor(v,2,64);  v += __shfl_xor(v,1,64);

// ---------------------------------------------------------------- transpose
// out[c*R + r] = in[r*Cc + c]
__global__ void k_transpose(const float* __restrict__ in, float* __restrict__ out, int R, int Cc){
    int i = blockIdx.x * 256 + threadIdx.x;
    if (i < R * Cc){ int r = i / Cc; int c = i - r * Cc; out[c * R + r] = in[i]; }
}

// ---------------------------------------------------------------- GCN + RMSNorm
// xg = rmsnorm(x @ gcn_w[0], g_norm_w); rows = 192000, C=128
__global__ __launch_bounds__(128) void k_gcn(const float* __restrict__ x, const float* __restrict__ gw,
                                             const float* __restrict__ gnw, float* __restrict__ xg){
    __shared__ float sx[16][128];
    __shared__ float part[16][2];
    __shared__ float srstd[16];
    int tid = threadIdx.x;
    int row0 = blockIdx.x * 16;
    for (int rr = 0; rr < 16; rr++) sx[rr][tid] = x[(row0 + rr) * 128 + tid];
    __syncthreads();
    float acc[16];
    #pragma unroll
    for (int rr = 0; rr < 16; rr++) acc[rr] = 0.f;
    for (int c = 0; c < 128; c += 4){
        float w0 = gw[(c+0)*128+tid], w1 = gw[(c+1)*128+tid];
        float w2 = gw[(c+2)*128+tid], w3 = gw[(c+3)*128+tid];
        #pragma unroll
        for (int rr = 0; rr < 16; rr++){
            float4 xv = *(const float4*)&sx[rr][c];
            acc[rr] = fmaf(xv.x,w0,fmaf(xv.y,w1,fmaf(xv.z,w2,fmaf(xv.w,w3,acc[rr]))));
        }
    }
    int lane = tid & 63, wv = tid >> 6;
    #pragma unroll
    for (int rr = 0; rr < 16; rr++){
        float v = acc[rr] * acc[rr];
        WAVE_RED(v)
        if (lane == 0) part[rr][wv] = v;
    }
    __syncthreads();
    if (tid < 16) srstd[tid] = rsqrtf((part[tid][0] + part[tid][1]) * 0.0078125f + 1e-6f);
    __syncthreads();
    float g = gnw[tid];
    for (int rr = 0; rr < 16; rr++) xg[(row0 + rr) * 128 + tid] = acc[rr] * srstd[rr] * g;
}

// ---------------------------------------------------------------- per-row token selection
// stable descending argsort of scores (ties: smaller index first), slot map, drop-softmax
__global__ void k_select(const float* __restrict__ sc, int* __restrict__ order,
                         int* __restrict__ slot, float* __restrict__ ph){
    int r = blockIdx.x * blockDim.x + threadIdx.x;
    if (r >= NTR) return;
    float s[NJ]; int id[NJ];
    for (int j = 0; j < NJ; j++){ s[j] = sc[r * NJ + j]; id[j] = j; }
    for (int m = 1; m < NJ; m++){
        float sv = s[m]; int iv = id[m]; int p = m;
        while (p > 0 && s[p-1] < sv){ s[p] = s[p-1]; id[p] = id[p-1]; p--; }
        s[p] = sv; id[p] = iv;
    }
    for (int j = 0; j < NJ; j++) order[r * NJ + j] = id[j];
    for (int i = 0; i < NKEEP; i++)  slot[r * NJ + id[i]] = 1 + i;
    for (int i = NKEEP; i < NJ; i++) slot[r * NJ + id[i]] = 18;
    float m8 = s[NKEEP];                      // sorted desc -> max of dropped
    float e[NDRP]; float sum = 0.f;
    for (int i = 0; i < NDRP; i++){ e[i] = expf(s[NKEEP + i] - m8); sum += e[i]; }
    float inv = 1.f / sum;
    for (int i = 0; i < NDRP; i++) ph[r * NDRP + i] = e[i] * inv;
}

// ---------------------------------------------------------------- spatial transformer (per NT row)
__global__ __launch_bounds__(128) void k_spatial(
    const float* __restrict__ xg, const int* __restrict__ order, const float* __restrict__ ph,
    const float* __restrict__ cls_tok, const float* __restrict__ sn1w, const float* __restrict__ sn2w,
    const float* __restrict__ WinT, const float* __restrict__ inb,
    const float* __restrict__ WoutT, const float* __restrict__ outb,
    const float* __restrict__ F1T, const float* __restrict__ f1b,
    const float* __restrict__ F2T, const float* __restrict__ f2b,
    float* __restrict__ delta, float* __restrict__ next_attn)
{
    __shared__ float xs[NL][128];      // x_slow -> x_msa -> rmsnorm2(x_msa)
    __shared__ float xnk[20][128];     // rmsnorm1 output; later overlaid as kT[4][32][20]
    __shared__ float qkv[NL][384];     // q|k|v ; then o -> [0:128), attn_out -> [128:256)
    __shared__ float attnm[4][NL][20];
    __shared__ float hbuf[NL][256];    // ffn hidden
    __shared__ float part[NL][2];
    __shared__ float srstd[NL];
    __shared__ int   keep_s[NKEEP];
    __shared__ int   drop_s[NDRP];
    __shared__ float ph_s[NDRP];

    int tid = threadIdx.x;
    int r = blockIdx.x;
    int lane = tid & 63, wv = tid >> 6;

    if (tid < NKEEP) keep_s[tid] = order[r * NJ + tid];
    else if (tid < NJ) drop_s[tid - NKEEP] = order[r * NJ + tid];
    if (tid < NDRP) ph_s[tid] = ph[r * NDRP + tid];
    __syncthreads();

    // build x_slow
    xs[0][tid] = cls_tok[tid];
    for (int i = 0; i < NKEEP; i++) xs[1 + i][tid] = xg[(r * NJ + keep_s[i]) * 128 + tid];
    {
        float rep = 0.f;
        for (int i = 0; i < NDRP; i++) rep += ph_s[i] * xg[(r * NJ + drop_s[i]) * 128 + tid];
        xs[18][tid] = rep;
    }
    __syncthreads();

    // rmsnorm1 -> xnk
    for (int row = 0; row < NL; row++){
        float v = xs[row][tid]; v *= v;
        WAVE_RED(v)
        if (lane == 0) part[row][wv] = v;
    }
    __syncthreads();
    if (tid < NL) srstd[tid] = rsqrtf((part[tid][0] + part[tid][1]) * 0.0078125f + 1e-6f);
    __syncthreads();
    {
        float s1 = sn1w[tid];
        for (int row = 0; row < NL; row++) xnk[row][tid] = xs[row][tid] * srstd[row] * s1;
    }
    __syncthreads();

    // qkv GEMM: thread owns output cols {tid, 128+tid, 256+tid}
    float acc[NL][3];
    for (int row = 0; row < NL; row++){ acc[row][0]=0.f; acc[row][1]=0.f; acc[row][2]=0.f; }
    for (int c = 0; c < 128; c += 4){
        float w[3][4];
        #pragma unroll
        for (int p = 0; p < 3; p++){
            w[p][0] = WinT[(c+0)*384 + p*128 + tid];
            w[p][1] = WinT[(c+1)*384 + p*128 + tid];
            w[p][2] = WinT[(c+2)*384 + p*128 + tid];
            w[p][3] = WinT[(c+3)*384 + p*128 + tid];
        }
        for (int row = 0; row < NL; row++){
            float4 xv = *(const float4*)&xnk[row][c];
            #pragma unroll
            for (int p = 0; p < 3; p++)
                acc[row][p] = fmaf(xv.x,w[p][0],fmaf(xv.y,w[p][1],fmaf(xv.z,w[p][2],fmaf(xv.w,w[p][3],acc[row][p]))));
        }
    }
    __syncthreads();   // xn fully consumed; overlay kT on xnk
    float (*kT)[32][20] = (float(*)[32][20])(&xnk[0][0]);
    {
        int hh = tid >> 5, cd = tid & 31;
        for (int row = 0; row < NL; row++){
            float q0 = acc[row][0] + inb[tid];
            float k0 = acc[row][1] + inb[128 + tid];
            float v0 = acc[row][2] + inb[256 + tid];
            qkv[row][tid]       = q0;
            qkv[row][256 + tid] = v0;
            kT[hh][cd][row]     = k0;
        }
    }
    __syncthreads();

    // logits (scaled)
    for (int idx = tid; idx < 4*NL*NL; idx += 128){
        int hh = idx / (NL*NL); int rem = idx - hh * (NL*NL); int i = rem / NL; int j = rem - i * NL;
        const float* qp = &qkv[i][hh * 32];
        float a = 0.f;
        #pragma unroll
        for (int cd = 0; cd < 32; cd++) a = fmaf(qp[cd], kT[hh][cd][j], a);
        attnm[hh][i][j] = a * 0.17677669529663687f;
    }
    __syncthreads();

    // softmax over keys
    if (tid < 4 * NL){
        int hh = tid / NL, i = tid - hh * NL;
        float m = attnm[hh][i][0];
        for (int j = 1; j < NL; j++) m = fmaxf(m, attnm[hh][i][j]);
        float s = 0.f;
        for (int j = 0; j < NL; j++){ float e = expf(attnm[hh][i][j] - m); attnm[hh][i][j] = e; s += e; }
        float inv = 1.f / s;
        for (int j = 0; j < NL; j++) attnm[hh][i][j] *= inv;
    }
    __syncthreads();

    // cls->others attention (head mean) -> next_attn scatter
    if (tid < 18){
        float v = 0.25f * (attnm[0][0][1+tid] + attnm[1][0][1+tid] + attnm[2][0][1+tid] + attnm[3][0][1+tid]);
        if (tid < NKEEP) next_attn[r * NJ + keep_s[tid]] = v;
        else { for (int i = 0; i < NDRP; i++) next_attn[r * NJ + drop_s[i]] = v; }
    }

    // o = attn @ v  (thread = channel)
    {
        float acc2[NL];
        #pragma unroll
        for (int i = 0; i < NL; i++) acc2[i] = 0.f;
        int hh = tid >> 5;
        for (int j = 0; j < NL; j++){
            float vv = qkv[j][256 + tid];
            #pragma unroll
            for (int i = 0; i < NL; i++) acc2[i] = fmaf(attnm[hh][i][j], vv, acc2[i]);
        }
        __syncthreads();
        for (int i = 0; i < NL; i++) qkv[i][tid] = acc2[i];   // o into q region
    }
    __syncthreads();

    // attn_out = o @ WoutT + b; x_msa = x_slow + attn_out
    {
        float acc3[NL];
        #pragma unroll
        for (int row = 0; row < NL; row++) acc3[row] = 0.f;
        for (int c = 0; c < 128; c += 4){
            float w0 = WoutT[(c+0)*128+tid], w1 = WoutT[(c+1)*128+tid];
            float w2 = WoutT[(c+2)*128+tid], w3 = WoutT[(c+3)*128+tid];
            for (int row = 0; row < NL; row++){
                float4 ov = *(const float4*)&qkv[row][c];
                acc3[row] = fmaf(ov.x,w0,fmaf(ov.y,w1,fmaf(ov.z,w2,fmaf(ov.w,w3,acc3[row]))));
            }
        }
        __syncthreads();
        float bo = outb[tid];
        for (int row = 0; row < NL; row++){
            float ao = acc3[row] + bo;
            qkv[row][128 + tid] = ao;      // save attn_out (k region is dead)
            xs[row][tid] += ao;            // x_msa
        }
    }
    __syncthreads();

    // rmsnorm2 in place on xs
    for (int row = 0; row < NL; row++){
        float v = xs[row][tid]; v *= v;
        WAVE_RED(v)
        if (lane == 0) part[row][wv] = v;
    }
    __syncthreads();
    if (tid < NL) srstd[tid] = rsqrtf((part[tid][0] + part[tid][1]) * 0.0078125f + 1e-6f);
    __syncthreads();
    {
        float s2 = sn2w[tid];
        for (int row = 0; row < NL; row++) xs[row][tid] *= srstd[row] * s2;
    }
    __syncthreads();

    // ffn1 + gelu -> hbuf
    {
        float acc40[NL], acc41[NL];
        #pragma unroll
        for (int row = 0; row < NL; row++){ acc40[row]=0.f; acc41[row]=0.f; }
        for (int c = 0; c < 128; c += 4){
            float wa0=F1T[(c+0)*256+tid],     wa1=F1T[(c+1)*256+tid];
            float wa2=F1T[(c+2)*256+tid],     wa3=F1T[(c+3)*256+tid];
            float wb0=F1T[(c+0)*256+128+tid], wb1=F1T[(c+1)*256+128+tid];
            float wb2=F1T[(c+2)*256+128+tid], wb3=F1T[(c+3)*256+128+tid];
            for (int row = 0; row < NL; row++){
                float4 xv = *(const float4*)&xs[row][c];
                acc40[row] = fmaf(xv.x,wa0,fmaf(xv.y,wa1,fmaf(xv.z,wa2,fmaf(xv.w,wa3,acc40[row]))));
                acc41[row] = fmaf(xv.x,wb0,fmaf(xv.y,wb1,fmaf(xv.z,wb2,fmaf(xv.w,wb3,acc41[row]))));
            }
        }
        float b0 = f1b[tid], b1 = f1b[128 + tid];
        for (int row = 0; row < NL; row++){
            hbuf[row][tid]       = gelu_exact(acc40[row] + b0);
            hbuf[row][128 + tid] = gelu_exact(acc41[row] + b1);
        }
    }
    __syncthreads();

    // ffn2 + delta = attn_out + ffn_out
    {
        float acc5[NL];
        #pragma unroll
        for (int row = 0; row < NL; row++) acc5[row] = 0.f;
        for (int kk = 0; kk < 256; kk += 4){
            float w0 = F2T[(kk+0)*128+tid], w1 = F2T[(kk+1)*128+tid];
            float w2 = F2T[(kk+2)*128+tid], w3 = F2T[(kk+3)*128+tid];
            for (int row = 0; row < NL; row++){
                float4 hv = *(const float4*)&hbuf[row][kk];
                acc5[row] = fmaf(hv.x,w0,fmaf(hv.y,w1,fmaf(hv.z,w2,fmaf(hv.w,w3,acc5[row]))));
            }
        }
        float b2 = f2b[tid];
        for (int row = 0; row < NL; row++)
            delta[(r * NL + row) * 128 + tid] = acc5[row] + b2 + qkv[row][128 + tid];
    }
}

// ---------------------------------------------------------------- scatter to temporal layout
// xsp[(n*25+j)*120+t][c] = 2*xg[(n*120+t)*25+j][c] + delta[r][slot][c]
__global__ void k_scatter(const float* __restrict__ xg, const float* __restrict__ delta,
                          const int* __restrict__ slot, float* __restrict__ xsp){
    int e = blockIdx.x * 256 + threadIdx.x;          // < 24,576,000
    int c = e & 127; int rem = e >> 7;               // rem = (n*25+j)*120 + t
    int t = rem % NTT; int nj = rem / NTT; int j = nj % NJ; int n = nj / NJ;
    int r = n * NTT + t;
    int sl = slot[r * NJ + j];
    xsp[e] = 2.0f * xg[(r * NJ + j) * 128 + c] + delta[(r * NL + sl) * 128 + c];
}

// ---------------------------------------------------------------- temporal attention (per seq, per head)
__global__ __launch_bounds__(128) void k_tattn(const float* __restrict__ xsp,
                                               const float* __restrict__ WqkvT,
                                               const float* __restrict__ inb,
                                               float* __restrict__ o){
    __shared__ __hip_bfloat16 xt_s[NTT][128];
    __shared__ __hip_bfloat16 q_s[NTT][32];
    __shared__ __hip_bfloat16 kT_s[32][128];   // [c][t], padded to 128
    __shared__ __hip_bfloat16 v_s[NTT][32];
    __shared__ float lg[40][NTT];
    int tid = threadIdx.x;
    int nj = blockIdx.x >> 2; int h = blockIdx.x & 3;
    const float* xrow = xsp + (size_t)nj * NTT * 128;
    {
        __hip_bfloat16* xf = &xt_s[0][0];
        for (int i = tid; i < NTT * 128; i += 128) xf[i] = __float2bfloat16(xrow[i]);
    }
    __syncthreads();

    // q,k,v for this head
    {
        int p = tid >> 5; int cc = tid & 31;
        if (p < 3){
            int col = p * 128 + h * 32 + cc;
            float bias = inb[col];
            for (int t0 = 0; t0 < NTT; t0 += 40){
                float acc[40];
                #pragma unroll
                for (int rr = 0; rr < 40; rr++) acc[rr] = 0.f;
                for (int cin = 0; cin < 128; cin += 2){
                    float w0 = WqkvT[cin * 384 + col];
                    float w1 = WqkvT[(cin + 1) * 384 + col];
                    #pragma unroll
                    for (int rr = 0; rr < 40; rr++){
                        __hip_bfloat162 xp = *(const __hip_bfloat162*)&xt_s[t0 + rr][cin];
                        acc[rr] = fmaf(__bfloat162float(xp.x), w0,
                                  fmaf(__bfloat162float(xp.y), w1, acc[rr]));
                    }
                }
                for (int rr = 0; rr < 40; rr++){
                    float v = acc[rr] + bias; int t = t0 + rr;
                    if (p == 0)      q_s[t][cc]  = __float2bfloat16(v);
                    else if (p == 1) kT_s[cc][t] = __float2bfloat16(v);
                    else             v_s[t][cc]  = __float2bfloat16(v);
                }
            }
        }
    }
    __syncthreads();

    for (int i0 = 0; i0 < NTT; i0 += 40){
        // logits tile 40 x 120
        for (int idx = tid; idx < 40 * NTT; idx += 128){
            int i = idx / NTT; int j = idx - i * NTT;
            float a = 0.f;
            #pragma unroll
            for (int cd = 0; cd < 32; cd++)
                a = fmaf(__bfloat162float(q_s[i0 + i][cd]), __bfloat162float(kT_s[cd][j]), a);
            lg[i][j] = a * 0.17677669529663687f;
        }
        __syncthreads();
        if (tid < 40){
            float m = lg[tid][0];
            for (int j = 1; j < NTT; j++) m = fmaxf(m, lg[tid][j]);
            float s = 0.f;
            for (int j = 0; j < NTT; j++){ float e = expf(lg[tid][j] - m); lg[tid][j] = e; s += e; }
            float inv = 1.f / s;
            for (int j = 0; j < NTT; j++) lg[tid][j] *= inv;
        }
        __syncthreads();
        {
            int cc2 = tid & 31;
            for (int ii = tid >> 5; ii < 40; ii += 4){
                float a = 0.f;
                for (int j = 0; j < NTT; j++)
                    a = fmaf(lg[ii][j], __bfloat162float(v_s[j][cc2]), a);
                o[((size_t)nj * NTT + i0 + ii) * 128 + h * 32 + cc2] = a;
            }
        }
        __syncthreads();
    }
}

// ---------------------------------------------------------------- temporal out-proj + residual + LN1
__global__ __launch_bounds__(128) void k_tout_ln1(
    const float* __restrict__ o, const float* __restrict__ WoutT, const float* __restrict__ ob,
    const float* __restrict__ xsp, const float* __restrict__ lnw, const float* __restrict__ lnb,
    float* __restrict__ xt1)
{
    __shared__ float so[16][128];
    __shared__ float prt[16][2][2];
    __shared__ float mv[16][2];
    int tid = threadIdx.x;
    int row0 = blockIdx.x * 16;
    for (int rr = 0; rr < 16; rr++) so[rr][tid] = o[(row0 + rr) * 128 + tid];
    __syncthreads();
    float acc[16];
    #pragma unroll
    for (int rr = 0; rr < 16; rr++) acc[rr] = 0.f;
    for (int c = 0; c < 128; c += 4){
        float w0 = WoutT[(c+0)*128+tid], w1 = WoutT[(c+1)*128+tid];
        float w2 = WoutT[(c+2)*128+tid], w3 = WoutT[(c+3)*128+tid];
        #pragma unroll
        for (int rr = 0; rr < 16; rr++){
            float4 ov = *(const float4*)&so[rr][c];
            acc[rr] = fmaf(ov.x,w0,fmaf(ov.y,w1,fmaf(ov.z,w2,fmaf(ov.w,w3,acc[rr]))));
        }
    }
    int lane = tid & 63, wv = tid >> 6;
    float bo = ob[tid];
    float y[16];
    for (int rr = 0; rr < 16; rr++) y[rr] = acc[rr] + bo + xsp[(row0 + rr) * 128 + tid];
    for (int rr = 0; rr < 16; rr++){
        float v = y[rr], v2 = v * v;
        WAVE_RED(v) WAVE_RED(v2)
        if (lane == 0){ prt[rr][wv][0] = v; prt[rr][wv][1] = v2; }
    }
    __syncthreads();
    if (tid < 16){
        float s = prt[tid][0][0] + prt[tid][1][0], s2 = prt[tid][0][1] + prt[tid][1][1];
        float m = s * 0.0078125f; float var = s2 * 0.0078125f - m * m;
        mv[tid][0] = m; mv[tid][1] = rsqrtf(var + 1e-5f);
    }
    __syncthreads();
    float lw = lnw[tid], lb = lnb[tid];
    for (int rr = 0; rr < 16; rr++)
        xt1[(row0 + rr) * 128 + tid] = (y[rr] - mv[rr][0]) * mv[rr][1] * lw + lb;
}

// ---------------------------------------------------------------- temporal FFN1 (gelu) -> bf16 hidden
__global__ __launch_bounds__(128) void k_tffn1(
    const float* __restrict__ xt1, const float* __restrict__ F1T, const float* __restrict__ f1b,
    __hip_bfloat16* __restrict__ hid)
{
    __shared__ float sx[8][128];
    int tid = threadIdx.x;
    int row0 = blockIdx.x * 8;
    for (int rr = 0; rr < 8; rr++) sx[rr][tid] = xt1[(row0 + rr) * 128 + tid];
    __syncthreads();
    float acc0[8], acc1[8];
    #pragma unroll
    for (int rr = 0; rr < 8; rr++){ acc0[rr] = 0.f; acc1[rr] = 0.f; }
    for (int c = 0; c < 128; c += 4){
        float wa0=F1T[(c+0)*256+tid],     wa1=F1T[(c+1)*256+tid];
        float wa2=F1T[(c+2)*256+tid],     wa3=F1T[(c+3)*256+tid];
        float wb0=F1T[(c+0)*256+128+tid], wb1=F1T[(c+1)*256+128+tid];
        float wb2=F1T[(c+2)*256+128+tid], wb3=F1T[(c+3)*256+128+tid];
        #pragma unroll
        for (int rr = 0; rr < 8; rr++){
            float4 xv = *(const float4*)&sx[rr][c];
            acc0[rr] = fmaf(xv.x,wa0,fmaf(xv.y,wa1,fmaf(xv.z,wa2,fmaf(xv.w,wa3,acc0[rr]))));
            acc1[rr] = fmaf(xv.x,wb0,fmaf(xv.y,wb1,fmaf(xv.z,wb2,fmaf(xv.w,wb3,acc1[rr]))));
        }
    }
    float b0 = f1b[tid], b1 = f1b[128 + tid];
    for (int rr = 0; rr < 8; rr++){
        hid[(row0 + rr) * 256 + tid]       = __float2bfloat16(gelu_exact(acc0[rr] + b0));
        hid[(row0 + rr) * 256 + 128 + tid] = __float2bfloat16(gelu_exact(acc1[rr] + b1));
    }
}

// ---------------------------------------------------------------- FFN2 + LN2 + RMSNorm + residuals -> out
__global__ __launch_bounds__(128) void k_final(
    const __hip_bfloat16* __restrict__ hid, const float* __restrict__ F2T, const float* __restrict__ f2b,
    const float* __restrict__ xt1, const float* __restrict__ ln2w, const float* __restrict__ ln2b,
    const float* __restrict__ tnw, const float* __restrict__ xsp, const float* __restrict__ x,
    float* __restrict__ out)
{
    __shared__ float sh[8][256];
    __shared__ float prt[8][2][2];
    __shared__ float mv[8][2];
    __shared__ float pr2[8][2];
    __shared__ float sr2[8];
    int tid = threadIdx.x;
    int row0 = blockIdx.x * 8;
    {
        float* shf = &sh[0][0];
        for (int i = tid; i < 8 * 256; i += 128) shf[i] = __bfloat162float(hid[row0 * 256 + i]);
    }
    __syncthreads();
    float acc[8];
    #pragma unroll
    for (int rr = 0; rr < 8; rr++) acc[rr] = 0.f;
    for (int kk = 0; kk < 256; kk += 4){
        float w0 = F2T[(kk+0)*128+tid], w1 = F2T[(kk+1)*128+tid];
        float w2 = F2T[(kk+2)*128+tid], w3 = F2T[(kk+3)*128+tid];
        #pragma unroll
        for (int rr = 0; rr < 8; rr++){
            float4 hv = *(const float4*)&sh[rr][kk];
            acc[rr] = fmaf(hv.x,w0,fmaf(hv.y,w1,fmaf(hv.z,w2,fmaf(hv.w,w3,acc[rr]))));
        }
    }
    int lane = tid & 63, wv = tid >> 6;
    float b2 = f2b[tid];
    float y[8];
    for (int rr = 0; rr < 8; rr++) y[rr] = acc[rr] + b2 + xt1[(row0 + rr) * 128 + tid];
    for (int rr = 0; rr < 8; rr++){
        float v = y[rr], v2 = v * v;
        WAVE_RED(v) WAVE_RED(v2)
        if (lane == 0){ prt[rr][wv][0] = v; prt[rr][wv][1] = v2; }
    }
    __syncthreads();
    if (tid < 8){
        float s = prt[tid][0][0] + prt[tid][1][0], s2 = prt[tid][0][1] + prt[tid][1][1];
        float m = s * 0.0078125f; float var = s2 * 0.0078125f - m * m;
        mv[tid][0] = m; mv[tid][1] = rsqrtf(var + 1e-5f);
    }
    __syncthreads();
    float z[8];
    float lw = ln2w[tid], lb = ln2b[tid];
    for (int rr = 0; rr < 8; rr++) z[rr] = (y[rr] - mv[rr][0]) * mv[rr][1] * lw + lb;
    for (int rr = 0; rr < 8; rr++){
        float v = z[rr] * z[rr];
        WAVE_RED(v)
        if (lane == 0) pr2[rr][wv] = v;
    }
    __syncthreads();
    if (tid < 8) sr2[tid] = rsqrtf((pr2[tid][0] + pr2[tid][1]) * 0.0078125f + 1e-6f);
    __syncthreads();
    float tw = tnw[tid];
    for (int rr = 0; rr < 8; rr++){
        int row = row0 + rr;
        int t = row % NTT; int nj = row / NTT; int j = nj % NJ; int n = nj / NJ;
        int xi = ((n * NTT + t) * NJ + j) * 128 + tid;
        out[xi] = z[rr] * sr2[rr] * tw + xsp[row * 128 + tid] + x[xi];
    }
}

// ================================================================ launch
extern "C" void kernel_launch(void* const* d_in, const int* in_sizes, int n_in,
                              void* d_out, int out_size, void* d_ws, size_t ws_size,
                              hipStream_t stream) {
    (void)in_sizes; (void)n_in; (void)out_size;
    const float* x      = (const float*)d_in[0];
    const float* sc     = (const float*)d_in[1];
    const float* gcnw   = (const float*)d_in[2];   // use gcn_w[0] (first 128*128)
    const float* gnw    = (const float*)d_in[3];
    const float* cls    = (const float*)d_in[4];
    const float* sn1    = (const float*)d_in[5];
    const float* sn2    = (const float*)d_in[6];
    const float* s_in_w = (const float*)d_in[7];
    const float* s_in_b = (const float*)d_in[8];
    const float* s_out_w= (const float*)d_in[9];
    const float* s_out_b= (const float*)d_in[10];
    const float* s_f1w  = (const float*)d_in[11];
    const float* s_f1b  = (const float*)d_in[12];
    const float* s_f2w  = (const float*)d_in[13];
    const float* s_f2b  = (const float*)d_in[14];
    const float* t_in_w = (const float*)d_in[15];
    const float* t_in_b = (const float*)d_in[16];
    const float* t_out_w= (const float*)d_in[17];
    const float* t_out_b= (const float*)d_in[18];
    const float* t_ln1w = (const float*)d_in[19];
    const float* t_ln1b = (const float*)d_in[20];
    const float* t_ln2w = (const float*)d_in[21];
    const float* t_ln2b = (const float*)d_in[22];
    const float* t_f1w  = (const float*)d_in[23];
    const float* t_f1b  = (const float*)d_in[24];
    const float* t_f2w  = (const float*)d_in[25];
    const float* t_f2b  = (const float*)d_in[26];
    const float* tnw    = (const float*)d_in[27];

    char* ws = (char*)d_ws;
    const size_t SZ_BIG = 98304000;                 // 192000*128*4
    float* R1 = (float*)ws;                         // x_gcn -> o -> hidden(bf16)
    float* R2 = (float*)(ws + SZ_BIG);              // x_sp (n,j,t,c)
    float* R3 = (float*)(ws + 2 * SZ_BIG);          // delta -> xt1
    char* p = ws + 3 * SZ_BIG;
    int*   ORD  = (int*)p;   p += 768000;
    int*   SLOT = (int*)p;   p += 768000;
    float* PH   = (float*)p; p += 245760;
    float* WTS  = (float*)p; p += 524288;
    float* WTT  = (float*)p; p += 524288;
    if (ws_size < (size_t)(p - ws)) return;          // ~298 MB required

    float* WinT_s  = WTS;
    float* WoutT_s = WTS + 49152;
    float* F1T_s   = WTS + 65536;
    float* F2T_s   = WTS + 98304;
    float* WinT_t  = WTT;
    float* WoutT_t = WTT + 49152;
    float* F1T_t   = WTT + 65536;
    float* F2T_t   = WTT + 98304;

    float* out0 = (float*)d_out;
    float* next_attn = out0 + 24576000;

    k_transpose<<<192, 256, 0, stream>>>(s_in_w,  WinT_s, 384, 128);
    k_transpose<<< 64, 256, 0, stream>>>(s_out_w, WoutT_s,128, 128);
    k_transpose<<<128, 256, 0, stream>>>(s_f1w,   F1T_s,  256, 128);
    k_transpose<<<128, 256, 0, stream>>>(s_f2w,   F2T_s,  128, 256);
    k_transpose<<<192, 256, 0, stream>>>(t_in_w,  WinT_t, 384, 128);
    k_transpose<<< 64, 256, 0, stream>>>(t_out_w, WoutT_t,128, 128);
    k_transpose<<<128, 256, 0, stream>>>(t_f1w,   F1T_t,  256, 128);
    k_transpose<<<128, 256, 0, stream>>>(t_f2w,   F2T_t,  128, 256);

    k_gcn<<<12000, 128, 0, stream>>>(x, gcnw, gnw, R1);
    k_select<<<30, 256, 0, stream>>>(sc, ORD, SLOT, PH);
    k_spatial<<<7680, 128, 0, stream>>>(R1, ORD, PH, cls, sn1, sn2,
                                        WinT_s, s_in_b, WoutT_s, s_out_b,
                                        F1T_s, s_f1b, F2T_s, s_f2b,
                                        R3, next_attn);
    k_scatter<<<96000, 256, 0, stream>>>(R1, R3, SLOT, R2);
    k_tattn<<<6400, 128, 0, stream>>>(R2, WinT_t, t_in_b, R1);            // o -> R1
    k_tout_ln1<<<12000, 128, 0, stream>>>(R1, WoutT_t, t_out_b, R2,
                                          t_ln1w, t_ln1b, R3);            // xt1 -> R3
    k_tffn1<<<24000, 128, 0, stream>>>(R3, F1T_t, t_f1b, (__hip_bfloat16*)R1);
    k_final<<<24000, 128, 0, stream>>>((const __hip_bfloat16*)R1, F2T_t, t_f2b,
                                       R3, t_ln2w, t_ln2b, tnw, R2, x, out0);
}

// Round 2
// 2598.864 us; speedup vs baseline: 1.8275x; 1.8275x over previous
//
#include <hip/hip_runtime.h>
#include <hip/hip_bf16.h>
#include <math.h>

// Problem constants
#define NTR   7680      // N*T
#define NJ    25
#define NKEEP 17
#define NDRP  8
#define NL    19        // 1 + 17 + 1
#define NROW  192000    // NT*J == N*J*T
#define NTT   120

typedef __attribute__((ext_vector_type(8))) short bf16x8;
typedef __attribute__((ext_vector_type(4))) float f32x4;

__device__ __forceinline__ float gelu_exact(float v){
    return 0.5f * v * (1.0f + erff(v * 0.70710678118654752440f));
}

__device__ __forceinline__ unsigned short f2bf(float v){
    union { float f; unsigned u; } a; a.f = v;
    unsigned r = a.u + 0x7FFF + ((a.u >> 16) & 1);   // RNE
    return (unsigned short)(r >> 16);
}

#define WAVE_RED(v) \
    v += __shfl_xor(v,32,64); v += __shfl_xor(v,16,64); v += __shfl_xor(v,8,64); \
    v += __shfl_xor(v,4,64);  v += __shfl_xor(v,2,64);  v += __shfl_xor(v,1,64);

// ---------------------------------------------------------------- transpose
// out[c*R + r] = in[r*Cc + c]
__global__ void k_transpose(const float* __restrict__ in, float* __restrict__ out, int R, int Cc){
    int i = blockIdx.x * 256 + threadIdx.x;
    if (i < R * Cc){ int r = i / Cc; int c = i - r * Cc; out[c * R + r] = in[i]; }
}

// ---------------------------------------------------------------- fp32 -> bf16 casts
__global__ void k_wcast(const float* __restrict__ in, unsigned short* __restrict__ out, int n4){
    int i = (blockIdx.x * 256 + threadIdx.x);
    if (i < n4){
        float4 v = *(const float4*)(in + i * 4);
        ushort4 o; o.x = f2bf(v.x); o.y = f2bf(v.y); o.z = f2bf(v.z); o.w = f2bf(v.w);
        *(ushort4*)(out + i * 4) = o;
    }
}

__global__ void k_xcast(const float* __restrict__ in, unsigned short* __restrict__ out){
    int i = (blockIdx.x * 256 + threadIdx.x) * 4;   // 24,576,000 elements total
    float4 v = *(const float4*)(in + i);
    ushort4 o; o.x = f2bf(v.x); o.y = f2bf(v.y); o.z = f2bf(v.z); o.w = f2bf(v.w);
    *(ushort4*)(out + i) = o;
}

// ---------------------------------------------------------------- GCN + RMSNorm
__global__ __launch_bounds__(128) void k_gcn(const float* __restrict__ x, const float* __restrict__ gw,
                                             const float* __restrict__ gnw, float* __restrict__ xg){
    __shared__ float sx[16][128];
    __shared__ float part[16][2];
    __shared__ float srstd[16];
    int tid = threadIdx.x;
    int row0 = blockIdx.x * 16;
    for (int rr = 0; rr < 16; rr++) sx[rr][tid] = x[(row0 + rr) * 128 + tid];
    __syncthreads();
    float acc[16];
    #pragma unroll
    for (int rr = 0; rr < 16; rr++) acc[rr] = 0.f;
    for (int c = 0; c < 128; c += 4){
        float w0 = gw[(c+0)*128+tid], w1 = gw[(c+1)*128+tid];
        float w2 = gw[(c+2)*128+tid], w3 = gw[(c+3)*128+tid];
        #pragma unroll
        for (int rr = 0; rr < 16; rr++){
            float4 xv = *(const float4*)&sx[rr][c];
            acc[rr] = fmaf(xv.x,w0,fmaf(xv.y,w1,fmaf(xv.z,w2,fmaf(xv.w,w3,acc[rr]))));
        }
    }
    int lane = tid & 63, wv = tid >> 6;
    #pragma unroll
    for (int rr = 0; rr < 16; rr++){
        float v = acc[rr] * acc[rr];
        WAVE_RED(v)
        if (lane == 0) part[rr][wv] = v;
    }
    __syncthreads();
    if (tid < 16) srstd[tid] = rsqrtf((part[tid][0] + part[tid][1]) * 0.0078125f + 1e-6f);
    __syncthreads();
    float g = gnw[tid];
    for (int rr = 0; rr < 16; rr++) xg[(row0 + rr) * 128 + tid] = acc[rr] * srstd[rr] * g;
}

// ---------------------------------------------------------------- per-row token selection
__global__ void k_select(const float* __restrict__ sc, int* __restrict__ order,
                         int* __restrict__ slot, float* __restrict__ ph){
    int r = blockIdx.x * blockDim.x + threadIdx.x;
    if (r >= NTR) return;
    float s[NJ]; int id[NJ];
    for (int j = 0; j < NJ; j++){ s[j] = sc[r * NJ + j]; id[j] = j; }
    for (int m = 1; m < NJ; m++){
        float sv = s[m]; int iv = id[m]; int p = m;
        while (p > 0 && s[p-1] < sv){ s[p] = s[p-1]; id[p] = id[p-1]; p--; }
        s[p] = sv; id[p] = iv;
    }
    for (int j = 0; j < NJ; j++) order[r * NJ + j] = id[j];
    for (int i = 0; i < NKEEP; i++)  slot[r * NJ + id[i]] = 1 + i;
    for (int i = NKEEP; i < NJ; i++) slot[r * NJ + id[i]] = 18;
    float m8 = s[NKEEP];
    float e[NDRP]; float sum = 0.f;
    for (int i = 0; i < NDRP; i++){ e[i] = expf(s[NKEEP + i] - m8); sum += e[i]; }
    float inv = 1.f / sum;
    for (int i = 0; i < NDRP; i++) ph[r * NDRP + i] = e[i] * inv;
}

// ---------------------------------------------------------------- spatial transformer (per NT row)
__global__ __launch_bounds__(128) void k_spatial(
    const float* __restrict__ xg, const int* __restrict__ order, const float* __restrict__ ph,
    const float* __restrict__ cls_tok, const float* __restrict__ sn1w, const float* __restrict__ sn2w,
    const float* __restrict__ WinT, const float* __restrict__ inb,
    const float* __restrict__ WoutT, const float* __restrict__ outb,
    const float* __restrict__ F1T, const float* __restrict__ f1b,
    const float* __restrict__ F2T, const float* __restrict__ f2b,
    float* __restrict__ delta, float* __restrict__ next_attn)
{
    __shared__ float xs[NL][128];
    __shared__ float xnk[20][128];
    __shared__ float qkv[NL][384];
    __shared__ float attnm[4][NL][20];
    __shared__ float hbuf[NL][256];
    __shared__ float part[NL][2];
    __shared__ float srstd[NL];
    __shared__ int   keep_s[NKEEP];
    __shared__ int   drop_s[NDRP];
    __shared__ float ph_s[NDRP];

    int tid = threadIdx.x;
    int r = blockIdx.x;
    int lane = tid & 63, wv = tid >> 6;

    if (tid < NKEEP) keep_s[tid] = order[r * NJ + tid];
    else if (tid < NJ) drop_s[tid - NKEEP] = order[r * NJ + tid];
    if (tid < NDRP) ph_s[tid] = ph[r * NDRP + tid];
    __syncthreads();

    xs[0][tid] = cls_tok[tid];
    for (int i = 0; i < NKEEP; i++) xs[1 + i][tid] = xg[(r * NJ + keep_s[i]) * 128 + tid];
    {
        float rep = 0.f;
        for (int i = 0; i < NDRP; i++) rep += ph_s[i] * xg[(r * NJ + drop_s[i]) * 128 + tid];
        xs[18][tid] = rep;
    }
    __syncthreads();

    for (int row = 0; row < NL; row++){
        float v = xs[row][tid]; v *= v;
        WAVE_RED(v)
        if (lane == 0) part[row][wv] = v;
    }
    __syncthreads();
    if (tid < NL) srstd[tid] = rsqrtf((part[tid][0] + part[tid][1]) * 0.0078125f + 1e-6f);
    __syncthreads();
    {
        float s1 = sn1w[tid];
        for (int row = 0; row < NL; row++) xnk[row][tid] = xs[row][tid] * srstd[row] * s1;
    }
    __syncthreads();

    float acc[NL][3];
    for (int row = 0; row < NL; row++){ acc[row][0]=0.f; acc[row][1]=0.f; acc[row][2]=0.f; }
    for (int c = 0; c < 128; c += 4){
        float w[3][4];
        #pragma unroll
        for (int p = 0; p < 3; p++){
            w[p][0] = WinT[(c+0)*384 + p*128 + tid];
            w[p][1] = WinT[(c+1)*384 + p*128 + tid];
            w[p][2] = WinT[(c+2)*384 + p*128 + tid];
            w[p][3] = WinT[(c+3)*384 + p*128 + tid];
        }
        for (int row = 0; row < NL; row++){
            float4 xv = *(const float4*)&xnk[row][c];
            #pragma unroll
            for (int p = 0; p < 3; p++)
                acc[row][p] = fmaf(xv.x,w[p][0],fmaf(xv.y,w[p][1],fmaf(xv.z,w[p][2],fmaf(xv.w,w[p][3],acc[row][p]))));
        }
    }
    __syncthreads();
    float (*kT)[32][20] = (float(*)[32][20])(&xnk[0][0]);
    {
        int hh = tid >> 5, cd = tid & 31;
        for (int row = 0; row < NL; row++){
            float q0 = acc[row][0] + inb[tid];
            float k0 = acc[row][1] + inb[128 + tid];
            float v0 = acc[row][2] + inb[256 + tid];
            qkv[row][tid]       = q0;
            qkv[row][256 + tid] = v0;
            kT[hh][cd][row]     = k0;
        }
    }
    __syncthreads();

    for (int idx = tid; idx < 4*NL*NL; idx += 128){
        int hh = idx / (NL*NL); int rem = idx - hh * (NL*NL); int i = rem / NL; int j = rem - i * NL;
        const float* qp = &qkv[i][hh * 32];
        float a = 0.f;
        #pragma unroll
        for (int cd = 0; cd < 32; cd++) a = fmaf(qp[cd], kT[hh][cd][j], a);
        attnm[hh][i][j] = a * 0.17677669529663687f;
    }
    __syncthreads();

    if (tid < 4 * NL){
        int hh = tid / NL, i = tid - hh * NL;
        float m = attnm[hh][i][0];
        for (int j = 1; j < NL; j++) m = fmaxf(m, attnm[hh][i][j]);
        float s = 0.f;
        for (int j = 0; j < NL; j++){ float e = expf(attnm[hh][i][j] - m); attnm[hh][i][j] = e; s += e; }
        float inv = 1.f / s;
        for (int j = 0; j < NL; j++) attnm[hh][i][j] *= inv;
    }
    __syncthreads();

    if (tid < 18){
        float v = 0.25f * (attnm[0][0][1+tid] + attnm[1][0][1+tid] + attnm[2][0][1+tid] + attnm[3][0][1+tid]);
        if (tid < NKEEP) next_attn[r * NJ + keep_s[tid]] = v;
        else { for (int i = 0; i < NDRP; i++) next_attn[r * NJ + drop_s[i]] = v; }
    }

    {
        float acc2[NL];
        #pragma unroll
        for (int i = 0; i < NL; i++) acc2[i] = 0.f;
        int hh = tid >> 5;
        for (int j = 0; j < NL; j++){
            float vv = qkv[j][256 + tid];
            #pragma unroll
            for (int i = 0; i < NL; i++) acc2[i] = fmaf(attnm[hh][i][j], vv, acc2[i]);
        }
        __syncthreads();
        for (int i = 0; i < NL; i++) qkv[i][tid] = acc2[i];
    }
    __syncthreads();

    {
        float acc3[NL];
        #pragma unroll
        for (int row = 0; row < NL; row++) acc3[row] = 0.f;
        for (int c = 0; c < 128; c += 4){
            float w0 = WoutT[(c+0)*128+tid], w1 = WoutT[(c+1)*128+tid];
            float w2 = WoutT[(c+2)*128+tid], w3 = WoutT[(c+3)*128+tid];
            for (int row = 0; row < NL; row++){
                float4 ov = *(const float4*)&qkv[row][c];
                acc3[row] = fmaf(ov.x,w0,fmaf(ov.y,w1,fmaf(ov.z,w2,fmaf(ov.w,w3,acc3[row]))));
            }
        }
        __syncthreads();
        float bo = outb[tid];
        for (int row = 0; row < NL; row++){
            float ao = acc3[row] + bo;
            qkv[row][128 + tid] = ao;
            xs[row][tid] += ao;
        }
    }
    __syncthreads();

    for (int row = 0; row < NL; row++){
        float v = xs[row][tid]; v *= v;
        WAVE_RED(v)
        if (lane == 0) part[row][wv] = v;
    }
    __syncthreads();
    if (tid < NL) srstd[tid] = rsqrtf((part[tid][0] + part[tid][1]) * 0.0078125f + 1e-6f);
    __syncthreads();
    {
        float s2 = sn2w[tid];
        for (int row = 0; row < NL; row++) xs[row][tid] *= srstd[row] * s2;
    }
    __syncthreads();

    {
        float acc40[NL], acc41[NL];
        #pragma unroll
        for (int row = 0; row < NL; row++){ acc40[row]=0.f; acc41[row]=0.f; }
        for (int c = 0; c < 128; c += 4){
            float wa0=F1T[(c+0)*256+tid],     wa1=F1T[(c+1)*256+tid];
            float wa2=F1T[(c+2)*256+tid],     wa3=F1T[(c+3)*256+tid];
            float wb0=F1T[(c+0)*256+128+tid], wb1=F1T[(c+1)*256+128+tid];
            float wb2=F1T[(c+2)*256+128+tid], wb3=F1T[(c+3)*256+128+tid];
            for (int row = 0; row < NL; row++){
                float4 xv = *(const float4*)&xs[row][c];
                acc40[row] = fmaf(xv.x,wa0,fmaf(xv.y,wa1,fmaf(xv.z,wa2,fmaf(xv.w,wa3,acc40[row]))));
                acc41[row] = fmaf(xv.x,wb0,fmaf(xv.y,wb1,fmaf(xv.z,wb2,fmaf(xv.w,wb3,acc41[row]))));
            }
        }
        float b0 = f1b[tid], b1 = f1b[128 + tid];
        for (int row = 0; row < NL; row++){
            hbuf[row][tid]       = gelu_exact(acc40[row] + b0);
            hbuf[row][128 + tid] = gelu_exact(acc41[row] + b1);
        }
    }
    __syncthreads();

    {
        float acc5[NL];
        #pragma unroll
        for (int row = 0; row < NL; row++) acc5[row] = 0.f;
        for (int kk = 0; kk < 256; kk += 4){
            float w0 = F2T[(kk+0)*128+tid], w1 = F2T[(kk+1)*128+tid];
            float w2 = F2T[(kk+2)*128+tid], w3 = F2T[(kk+3)*128+tid];
            for (int row = 0; row < NL; row++){
                float4 hv = *(const float4*)&hbuf[row][kk];
                acc5[row] = fmaf(hv.x,w0,fmaf(hv.y,w1,fmaf(hv.z,w2,fmaf(hv.w,w3,acc5[row]))));
            }
        }
        float b2 = f2b[tid];
        for (int row = 0; row < NL; row++)
            delta[(r * NL + row) * 128 + tid] = acc5[row] + b2 + qkv[row][128 + tid];
    }
}

// ---------------------------------------------------------------- scatter to temporal layout
__global__ void k_scatter(const float* __restrict__ xg, const float* __restrict__ delta,
                          const int* __restrict__ slot, float* __restrict__ xsp){
    int e = blockIdx.x * 256 + threadIdx.x;
    int c = e & 127; int rem = e >> 7;
    int t = rem % NTT; int nj = rem / NTT; int j = nj % NJ; int n = nj / NJ;
    int r = n * NTT + t;
    int sl = slot[r * NJ + j];
    xsp[e] = 2.0f * xg[(r * NJ + j) * 128 + c] + delta[(r * NL + sl) * 128 + c];
}

// ---------------------------------------------------------------- temporal attention: MFMA, 1 wave = (nj, head)
// xb: bf16 [1600*120][128] (+8 rows pad), Wb: bf16 [384][128] (= t_in_w layout)
__global__ __launch_bounds__(64) void k_tattn_mfma(
    const unsigned short* __restrict__ xb, const unsigned short* __restrict__ Wb,
    const float* __restrict__ inb, float* __restrict__ o)
{
    // LDS: q[120][40] | k[120][40] | vT[32][136] | P[16][136]  (all bf16) = 32,256 B
    __shared__ __align__(16) unsigned short smem[16128];
    unsigned short* q_s = smem;
    unsigned short* k_s = smem + 4800;
    unsigned short* vT  = smem + 9600;
    unsigned short* P_s = smem + 13952;

    int l  = threadIdx.x;
    int cl = l & 15;
    int g  = l >> 4;
    int nj = blockIdx.x >> 2;
    int h  = blockIdx.x & 3;

    // zero vT key-pad columns 120..127
    for (int i = l; i < 256; i += 64) vT[(i >> 3) * 136 + 120 + (i & 7)] = 0;

    const unsigned short* xrow = xb + (size_t)nj * (NTT * 128);
    const float scale = 0.17677669529663687f;

    // ---- QKV projection (per-head 96 columns), MFMA 16x16x32 ----
    bf16x8 bfr[6][4];
    float bias[6];
    #pragma unroll
    for (int pc = 0; pc < 6; ++pc){
        int p = pc >> 1, s = pc & 1;
        int col = p * 128 + h * 32 + s * 16 + cl;
        bias[pc] = inb[col];
        #pragma unroll
        for (int ks = 0; ks < 4; ++ks)
            bfr[pc][ks] = *(const bf16x8*)(Wb + col * 128 + ks * 32 + g * 8);
    }

    for (int mt = 0; mt < 8; ++mt){
        bf16x8 af[4];
        #pragma unroll
        for (int ks = 0; ks < 4; ++ks)
            af[ks] = *(const bf16x8*)(xrow + (mt * 16 + cl) * 128 + ks * 32 + g * 8);
        #pragma unroll
        for (int pc = 0; pc < 6; ++pc){
            f32x4 acc = {0.f, 0.f, 0.f, 0.f};
            #pragma unroll
            for (int ks = 0; ks < 4; ++ks)
                acc = __builtin_amdgcn_mfma_f32_16x16x32_bf16(af[ks], bfr[pc][ks], acc, 0, 0, 0);
            int p = pc >> 1, s = pc & 1;
            int d = s * 16 + cl;
            #pragma unroll
            for (int reg = 0; reg < 4; ++reg){
                int t = mt * 16 + g * 4 + reg;
                if (t < NTT){
                    float v = acc[reg] + bias[pc];
                    if (p == 0)      q_s[t * 40 + d] = f2bf(v * scale);
                    else if (p == 1) k_s[t * 40 + d] = f2bf(v);
                    else             vT[d * 136 + t] = f2bf(v);
                }
            }
        }
    }
    __syncthreads();

    // ---- attention: per 16-query tile ----
    for (int mt = 0; mt < 8; ++mt){
        bf16x8 aq = *(const bf16x8*)(q_s + (mt * 16 + cl) * 40 + g * 8);
        f32x4 lg[8];
        #pragma unroll
        for (int jt = 0; jt < 8; ++jt){
            bf16x8 bk = *(const bf16x8*)(k_s + (jt * 16 + cl) * 40 + g * 8);
            f32x4 z = {0.f, 0.f, 0.f, 0.f};
            lg[jt] = __builtin_amdgcn_mfma_f32_16x16x32_bf16(aq, bk, z, 0, 0, 0);
        }
        if (cl >= 8){ lg[7][0] = -1e30f; lg[7][1] = -1e30f; lg[7][2] = -1e30f; lg[7][3] = -1e30f; }

        float inv[4];
        #pragma unroll
        for (int reg = 0; reg < 4; ++reg){
            float m = lg[0][reg];
            #pragma unroll
            for (int jt = 1; jt < 8; ++jt) m = fmaxf(m, lg[jt][reg]);
            m = fmaxf(m, __shfl_xor(m, 1, 64));
            m = fmaxf(m, __shfl_xor(m, 2, 64));
            m = fmaxf(m, __shfl_xor(m, 4, 64));
            m = fmaxf(m, __shfl_xor(m, 8, 64));
            float s = 0.f;
            #pragma unroll
            for (int jt = 0; jt < 8; ++jt){ float e = __expf(lg[jt][reg] - m); lg[jt][reg] = e; s += e; }
            s += __shfl_xor(s, 1, 64); s += __shfl_xor(s, 2, 64);
            s += __shfl_xor(s, 4, 64); s += __shfl_xor(s, 8, 64);
            inv[reg] = 1.f / s;
        }

        __syncthreads();   // WAR: previous tile's PV reads of P_s finished
        #pragma unroll
        for (int jt = 0; jt < 8; ++jt){
            #pragma unroll
            for (int reg = 0; reg < 4; ++reg)
                P_s[(g * 4 + reg) * 136 + jt * 16 + cl] = f2bf(lg[jt][reg] * inv[reg]);
        }
        __syncthreads();   // P visible

        bf16x8 ap[4];
        #pragma unroll
        for (int ks = 0; ks < 4; ++ks)
            ap[ks] = *(const bf16x8*)(P_s + cl * 136 + ks * 32 + g * 8);
        #pragma unroll
        for (int nt = 0; nt < 2; ++nt){
            f32x4 oacc = {0.f, 0.f, 0.f, 0.f};
            #pragma unroll
            for (int ks = 0; ks < 4; ++ks){
                bf16x8 bv = *(const bf16x8*)(vT + (nt * 16 + cl) * 136 + ks * 32 + g * 8);
                oacc = __builtin_amdgcn_mfma_f32_16x16x32_bf16(ap[ks], bv, oacc, 0, 0, 0);
            }
            #pragma unroll
            for (int reg = 0; reg < 4; ++reg){
                int t = mt * 16 + g * 4 + reg;
                if (t < NTT)
                    o[((size_t)nj * NTT + t) * 128 + h * 32 + nt * 16 + cl] = oacc[reg];
            }
        }
    }
}

// ---------------------------------------------------------------- temporal out-proj + residual + LN1
__global__ __launch_bounds__(128) void k_tout_ln1(
    const float* __restrict__ o, const float* __restrict__ WoutT, const float* __restrict__ ob,
    const float* __restrict__ xsp, const float* __restrict__ lnw, const float* __restrict__ lnb,
    float* __restrict__ xt1)
{
    __shared__ float so[16][128];
    __shared__ float prt[16][2][2];
    __shared__ float mv[16][2];
    int tid = threadIdx.x;
    int row0 = blockIdx.x * 16;
    for (int rr = 0; rr < 16; rr++) so[rr][tid] = o[(row0 + rr) * 128 + tid];
    __syncthreads();
    float acc[16];
    #pragma unroll
    for (int rr = 0; rr < 16; rr++) acc[rr] = 0.f;
    for (int c = 0; c < 128; c += 4){
        float w0 = WoutT[(c+0)*128+tid], w1 = WoutT[(c+1)*128+tid];
        float w2 = WoutT[(c+2)*128+tid], w3 = WoutT[(c+3)*128+tid];
        #pragma unroll
        for (int rr = 0; rr < 16; rr++){
            float4 ov = *(const float4*)&so[rr][c];
            acc[rr] = fmaf(ov.x,w0,fmaf(ov.y,w1,fmaf(ov.z,w2,fmaf(ov.w,w3,acc[rr]))));
        }
    }
    int lane = tid & 63, wv = tid >> 6;
    float bo = ob[tid];
    float y[16];
    for (int rr = 0; rr < 16; rr++) y[rr] = acc[rr] + bo + xsp[(row0 + rr) * 128 + tid];
    for (int rr = 0; rr < 16; rr++){
        float v = y[rr], v2 = v * v;
        WAVE_RED(v) WAVE_RED(v2)
        if (lane == 0){ prt[rr][wv][0] = v; prt[rr][wv][1] = v2; }
    }
    __syncthreads();
    if (tid < 16){
        float s = prt[tid][0][0] + prt[tid][1][0], s2 = prt[tid][0][1] + prt[tid][1][1];
        float m = s * 0.0078125f; float var = s2 * 0.0078125f - m * m;
        mv[tid][0] = m; mv[tid][1] = rsqrtf(var + 1e-5f);
    }
    __syncthreads();
    float lw = lnw[tid], lb = lnb[tid];
    for (int rr = 0; rr < 16; rr++)
        xt1[(row0 + rr) * 128 + tid] = (y[rr] - mv[rr][0]) * mv[rr][1] * lw + lb;
}

// ---------------------------------------------------------------- temporal FFN1 (gelu) -> bf16 hidden
__global__ __launch_bounds__(128) void k_tffn1(
    const float* __restrict__ xt1, const float* __restrict__ F1T, const float* __restrict__ f1b,
    __hip_bfloat16* __restrict__ hid)
{
    __shared__ float sx[8][128];
    int tid = threadIdx.x;
    int row0 = blockIdx.x * 8;
    for (int rr = 0; rr < 8; rr++) sx[rr][tid] = xt1[(row0 + rr) * 128 + tid];
    __syncthreads();
    float acc0[8], acc1[8];
    #pragma unroll
    for (int rr = 0; rr < 8; rr++){ acc0[rr] = 0.f; acc1[rr] = 0.f; }
    for (int c = 0; c < 128; c += 4){
        float wa0=F1T[(c+0)*256+tid],     wa1=F1T[(c+1)*256+tid];
        float wa2=F1T[(c+2)*256+tid],     wa3=F1T[(c+3)*256+tid];
        float wb0=F1T[(c+0)*256+128+tid], wb1=F1T[(c+1)*256+128+tid];
        float wb2=F1T[(c+2)*256+128+tid], wb3=F1T[(c+3)*256+128+tid];
        #pragma unroll
        for (int rr = 0; rr < 8; rr++){
            float4 xv = *(const float4*)&sx[rr][c];
            acc0[rr] = fmaf(xv.x,wa0,fmaf(xv.y,wa1,fmaf(xv.z,wa2,fmaf(xv.w,wa3,acc0[rr]))));
            acc1[rr] = fmaf(xv.x,wb0,fmaf(xv.y,wb1,fmaf(xv.z,wb2,fmaf(xv.w,wb3,acc1[rr]))));
        }
    }
    float b0 = f1b[tid], b1 = f1b[128 + tid];
    for (int rr = 0; rr < 8; rr++){
        hid[(row0 + rr) * 256 + tid]       = __float2bfloat16(gelu_exact(acc0[rr] + b0));
        hid[(row0 + rr) * 256 + 128 + tid] = __float2bfloat16(gelu_exact(acc1[rr] + b1));
    }
}

// ---------------------------------------------------------------- FFN2 + LN2 + RMSNorm + residuals -> out
__global__ __launch_bounds__(128) void k_final(
    const __hip_bfloat16* __restrict__ hid, const float* __restrict__ F2T, const float* __restrict__ f2b,
    const float* __restrict__ xt1, const float* __restrict__ ln2w, const float* __restrict__ ln2b,
    const float* __restrict__ tnw, const float* __restrict__ xsp, const float* __restrict__ x,
    float* __restrict__ out)
{
    __shared__ float sh[8][256];
    __shared__ float prt[8][2][2];
    __shared__ float mv[8][2];
    __shared__ float pr2[8][2];
    __shared__ float sr2[8];
    int tid = threadIdx.x;
    int row0 = blockIdx.x * 8;
    {
        float* shf = &sh[0][0];
        for (int i = tid; i < 8 * 256; i += 128) shf[i] = __bfloat162float(hid[row0 * 256 + i]);
    }
    __syncthreads();
    float acc[8];
    #pragma unroll
    for (int rr = 0; rr < 8; rr++) acc[rr] = 0.f;
    for (int kk = 0; kk < 256; kk += 4){
        float w0 = F2T[(kk+0)*128+tid], w1 = F2T[(kk+1)*128+tid];
        float w2 = F2T[(kk+2)*128+tid], w3 = F2T[(kk+3)*128+tid];
        #pragma unroll
        for (int rr = 0; rr < 8; rr++){
            float4 hv = *(const float4*)&sh[rr][kk];
            acc[rr] = fmaf(hv.x,w0,fmaf(hv.y,w1,fmaf(hv.z,w2,fmaf(hv.w,w3,acc[rr]))));
        }
    }
    int lane = tid & 63, wv = tid >> 6;
    float b2 = f2b[tid];
    float y[8];
    for (int rr = 0; rr < 8; rr++) y[rr] = acc[rr] + b2 + xt1[(row0 + rr) * 128 + tid];
    for (int rr = 0; rr < 8; rr++){
        float v = y[rr], v2 = v * v;
        WAVE_RED(v) WAVE_RED(v2)
        if (lane == 0){ prt[rr][wv][0] = v; prt[rr][wv][1] = v2; }
    }
    __syncthreads();
    if (tid < 8){
        float s = prt[tid][0][0] + prt[tid][1][0], s2 = prt[tid][0][1] + prt[tid][1][1];
        float m = s * 0.0078125f; float var = s2 * 0.0078125f - m * m;
        mv[tid][0] = m; mv[tid][1] = rsqrtf(var + 1e-5f);
    }
    __syncthreads();
    float z[8];
    float lw = ln2w[tid], lb = ln2b[tid];
    for (int rr = 0; rr < 8; rr++) z[rr] = (y[rr] - mv[rr][0]) * mv[rr][1] * lw + lb;
    for (int rr = 0; rr < 8; rr++){
        float v = z[rr] * z[rr];
        WAVE_RED(v)
        if (lane == 0) pr2[rr][wv] = v;
    }
    __syncthreads();
    if (tid < 8) sr2[tid] = rsqrtf((pr2[tid][0] + pr2[tid][1]) * 0.0078125f + 1e-6f);
    __syncthreads();
    float tw = tnw[tid];
    for (int rr = 0; rr < 8; rr++){
        int row = row0 + rr;
        int t = row % NTT; int nj = row / NTT; int j = nj % NJ; int n = nj / NJ;
        int xi = ((n * NTT + t) * NJ + j) * 128 + tid;
        out[xi] = z[rr] * sr2[rr] * tw + xsp[row * 128 + tid] + x[xi];
    }
}

// ================================================================ launch
extern "C" void kernel_launch(void* const* d_in, const int* in_sizes, int n_in,
                              void* d_out, int out_size, void* d_ws, size_t ws_size,
                              hipStream_t stream) {
    (void)in_sizes; (void)n_in; (void)out_size;
    const float* x      = (const float*)d_in[0];
    const float* sc     = (const float*)d_in[1];
    const float* gcnw   = (const float*)d_in[2];
    const float* gnw    = (const float*)d_in[3];
    const float* cls    = (const float*)d_in[4];
    const float* sn1    = (const float*)d_in[5];
    const float* sn2    = (const float*)d_in[6];
    const float* s_in_w = (const float*)d_in[7];
    const float* s_in_b = (const float*)d_in[8];
    const float* s_out_w= (const float*)d_in[9];
    const float* s_out_b= (const float*)d_in[10];
    const float* s_f1w  = (const float*)d_in[11];
    const float* s_f1b  = (const float*)d_in[12];
    const float* s_f2w  = (const float*)d_in[13];
    const float* s_f2b  = (const float*)d_in[14];
    const float* t_in_w = (const float*)d_in[15];
    const float* t_in_b = (const float*)d_in[16];
    const float* t_out_w= (const float*)d_in[17];
    const float* t_out_b= (const float*)d_in[18];
    const float* t_ln1w = (const float*)d_in[19];
    const float* t_ln1b = (const float*)d_in[20];
    const float* t_ln2w = (const float*)d_in[21];
    const float* t_ln2b = (const float*)d_in[22];
    const float* t_f1w  = (const float*)d_in[23];
    const float* t_f1b  = (const float*)d_in[24];
    const float* t_f2w  = (const float*)d_in[25];
    const float* t_f2b  = (const float*)d_in[26];
    const float* tnw    = (const float*)d_in[27];

    char* ws = (char*)d_ws;
    const size_t SZ_BIG = 98304000;                 // 192000*128*4
    float* R1 = (float*)ws;                         // x_gcn -> o -> hidden(bf16)
    float* R2 = (float*)(ws + SZ_BIG);              // x_sp (n,j,t,c)
    float* R3 = (float*)(ws + 2 * SZ_BIG);          // delta -> xb(bf16) -> xt1
    char* p = ws + 3 * SZ_BIG;
    int*   ORD  = (int*)p;   p += 768000;
    int*   SLOT = (int*)p;   p += 768000;
    float* PH   = (float*)p; p += 245760;
    float* WTS  = (float*)p; p += 524288;
    float* WTT  = (float*)p; p += 524288;
    unsigned short* WB = (unsigned short*)p; p += 98304;   // t_in_w bf16 [384][128]
    if (ws_size < (size_t)(p - ws)) return;

    float* WinT_s  = WTS;
    float* WoutT_s = WTS + 49152;
    float* F1T_s   = WTS + 65536;
    float* F2T_s   = WTS + 98304;
    float* WoutT_t = WTT + 49152;
    float* F1T_t   = WTT + 65536;
    float* F2T_t   = WTT + 98304;
    unsigned short* XB = (unsigned short*)R3;       // bf16 x for temporal attn (49.15 MB < R3)

    float* out0 = (float*)d_out;
    float* next_attn = out0 + 24576000;

    k_transpose<<<192, 256, 0, stream>>>(s_in_w,  WinT_s, 384, 128);
    k_transpose<<< 64, 256, 0, stream>>>(s_out_w, WoutT_s,128, 128);
    k_transpose<<<128, 256, 0, stream>>>(s_f1w,   F1T_s,  256, 128);
    k_transpose<<<128, 256, 0, stream>>>(s_f2w,   F2T_s,  128, 256);
    k_transpose<<< 64, 256, 0, stream>>>(t_out_w, WoutT_t,128, 128);
    k_transpose<<<128, 256, 0, stream>>>(t_f1w,   F1T_t,  256, 128);
    k_transpose<<<128, 256, 0, stream>>>(t_f2w,   F2T_t,  128, 256);
    k_wcast<<<48, 256, 0, stream>>>(t_in_w, WB, 12288);

    k_gcn<<<12000, 128, 0, stream>>>(x, gcnw, gnw, R1);
    k_select<<<30, 256, 0, stream>>>(sc, ORD, SLOT, PH);
    k_spatial<<<7680, 128, 0, stream>>>(R1, ORD, PH, cls, sn1, sn2,
                                        WinT_s, s_in_b, WoutT_s, s_out_b,
                                        F1T_s, s_f1b, F2T_s, s_f2b,
                                        R3, next_attn);
    k_scatter<<<96000, 256, 0, stream>>>(R1, R3, SLOT, R2);
    k_xcast<<<24000, 256, 0, stream>>>(R2, XB);                            // delta dead; R3 -> xb
    k_tattn_mfma<<<6400, 64, 0, stream>>>(XB, WB, t_in_b, R1);             // o -> R1
    k_tout_ln1<<<12000, 128, 0, stream>>>(R1, WoutT_t, t_out_b, R2,
                                          t_ln1w, t_ln1b, R3);             // xt1 -> R3 (xb dead)
    k_tffn1<<<24000, 128, 0, stream>>>(R3, F1T_t, t_f1b, (__hip_bfloat16*)R1);
    k_final<<<24000, 128, 0, stream>>>((const __hip_bfloat16*)R1, F2T_t, t_f2b,
                                       R3, t_ln2w, t_ln2b, tnw, R2, x, out0);
}

// Round 3
// 1791.006 us; speedup vs baseline: 2.6519x; 1.4511x over previous
//
#include <hip/hip_runtime.h>
#include <hip/hip_bf16.h>
#include <math.h>

// Problem constants
#define NTR   7680      // N*T
#define NJ    25
#define NKEEP 17
#define NDRP  8
#define NL    19        // 1 + 17 + 1
#define NROW  192000    // NT*J == N*J*T
#define NTT   120

typedef __attribute__((ext_vector_type(8))) short bf16x8;
typedef __attribute__((ext_vector_type(4))) float f32x4;

__device__ __forceinline__ float gelu_exact(float v){
    return 0.5f * v * (1.0f + erff(v * 0.70710678118654752440f));
}

__device__ __forceinline__ unsigned short f2bf(float v){
    union { float f; unsigned u; } a; a.f = v;
    unsigned r = a.u + 0x7FFF + ((a.u >> 16) & 1);   // RNE
    return (unsigned short)(r >> 16);
}

__device__ __forceinline__ float bf2f(unsigned short u){
    union { unsigned u; float f; } a; a.u = ((unsigned)u) << 16; return a.f;
}

#define WAVE_RED(v) \
    v += __shfl_xor(v,32,64); v += __shfl_xor(v,16,64); v += __shfl_xor(v,8,64); \
    v += __shfl_xor(v,4,64);  v += __shfl_xor(v,2,64);  v += __shfl_xor(v,1,64);

// ---------------------------------------------------------------- transpose
// out[c*R + r] = in[r*Cc + c]
__global__ void k_transpose(const float* __restrict__ in, float* __restrict__ out, int R, int Cc){
    int i = blockIdx.x * 256 + threadIdx.x;
    if (i < R * Cc){ int r = i / Cc; int c = i - r * Cc; out[c * R + r] = in[i]; }
}

// ---------------------------------------------------------------- fp32 -> bf16 casts
__global__ void k_wcast(const float* __restrict__ in, unsigned short* __restrict__ out, int n4){
    int i = (blockIdx.x * 256 + threadIdx.x);
    if (i < n4){
        float4 v = *(const float4*)(in + i * 4);
        ushort4 o; o.x = f2bf(v.x); o.y = f2bf(v.y); o.z = f2bf(v.z); o.w = f2bf(v.w);
        *(ushort4*)(out + i * 4) = o;
    }
}

__global__ void k_xcast(const float* __restrict__ in, unsigned short* __restrict__ out){
    int i = (blockIdx.x * 256 + threadIdx.x) * 4;   // 24,576,000 elements total
    float4 v = *(const float4*)(in + i);
    ushort4 o; o.x = f2bf(v.x); o.y = f2bf(v.y); o.z = f2bf(v.z); o.w = f2bf(v.w);
    *(ushort4*)(out + i) = o;
}

// ---------------------------------------------------------------- GCN + RMSNorm
__global__ __launch_bounds__(128) void k_gcn(const float* __restrict__ x, const float* __restrict__ gw,
                                             const float* __restrict__ gnw, float* __restrict__ xg){
    __shared__ float sx[16][128];
    __shared__ float part[16][2];
    __shared__ float srstd[16];
    int tid = threadIdx.x;
    int row0 = blockIdx.x * 16;
    for (int rr = 0; rr < 16; rr++) sx[rr][tid] = x[(row0 + rr) * 128 + tid];
    __syncthreads();
    float acc[16];
    #pragma unroll
    for (int rr = 0; rr < 16; rr++) acc[rr] = 0.f;
    for (int c = 0; c < 128; c += 4){
        float w0 = gw[(c+0)*128+tid], w1 = gw[(c+1)*128+tid];
        float w2 = gw[(c+2)*128+tid], w3 = gw[(c+3)*128+tid];
        #pragma unroll
        for (int rr = 0; rr < 16; rr++){
            float4 xv = *(const float4*)&sx[rr][c];
            acc[rr] = fmaf(xv.x,w0,fmaf(xv.y,w1,fmaf(xv.z,w2,fmaf(xv.w,w3,acc[rr]))));
        }
    }
    int lane = tid & 63, wv = tid >> 6;
    #pragma unroll
    for (int rr = 0; rr < 16; rr++){
        float v = acc[rr] * acc[rr];
        WAVE_RED(v)
        if (lane == 0) part[rr][wv] = v;
    }
    __syncthreads();
    if (tid < 16) srstd[tid] = rsqrtf((part[tid][0] + part[tid][1]) * 0.0078125f + 1e-6f);
    __syncthreads();
    float g = gnw[tid];
    for (int rr = 0; rr < 16; rr++) xg[(row0 + rr) * 128 + tid] = acc[rr] * srstd[rr] * g;
}

// ---------------------------------------------------------------- per-row token selection
__global__ void k_select(const float* __restrict__ sc, int* __restrict__ order,
                         int* __restrict__ slot, float* __restrict__ ph){
    int r = blockIdx.x * blockDim.x + threadIdx.x;
    if (r >= NTR) return;
    float s[NJ]; int id[NJ];
    for (int j = 0; j < NJ; j++){ s[j] = sc[r * NJ + j]; id[j] = j; }
    for (int m = 1; m < NJ; m++){
        float sv = s[m]; int iv = id[m]; int p = m;
        while (p > 0 && s[p-1] < sv){ s[p] = s[p-1]; id[p] = id[p-1]; p--; }
        s[p] = sv; id[p] = iv;
    }
    for (int j = 0; j < NJ; j++) order[r * NJ + j] = id[j];
    for (int i = 0; i < NKEEP; i++)  slot[r * NJ + id[i]] = 1 + i;
    for (int i = NKEEP; i < NJ; i++) slot[r * NJ + id[i]] = 18;
    float m8 = s[NKEEP];
    float e[NDRP]; float sum = 0.f;
    for (int i = 0; i < NDRP; i++){ e[i] = expf(s[NKEEP + i] - m8); sum += e[i]; }
    float inv = 1.f / sum;
    for (int i = 0; i < NDRP; i++) ph[r * NDRP + i] = e[i] * inv;
}

// ---------------------------------------------------------------- spatial transformer, MFMA, 2 r's per block
// LDS ushort layout: xs[48][136] | xn[48][136] | qb[48][392]
// am (f32 [8][19][20]) overlays xn during attention.
__global__ __launch_bounds__(128) void k_spatial_mfma(
    const float* __restrict__ xg, const int* __restrict__ order, const float* __restrict__ ph,
    const float* __restrict__ cls_tok, const float* __restrict__ sn1w, const float* __restrict__ sn2w,
    const unsigned short* __restrict__ WinB, const float* __restrict__ inb,
    const unsigned short* __restrict__ WoutB, const float* __restrict__ outb,
    const unsigned short* __restrict__ F1B, const float* __restrict__ f1b,
    const unsigned short* __restrict__ F2B, const float* __restrict__ f2b,
    unsigned short* __restrict__ delta, float* __restrict__ next_attn)
{
    __shared__ __align__(16) unsigned short sm[31872];
    __shared__ float rstd[48];
    __shared__ int   ord_s[2][NJ];
    __shared__ float ph_s[2][NDRP];
    unsigned short* xs = sm;               // [48][136] x_slow -> x_msa (bf16)
    unsigned short* xn = sm + 6528;        // [48][136] rmsnorm out (bf16)
    unsigned short* qb = sm + 13056;       // [48][392] q|k|v ; o->q, attn_out->k, h->(q,v)
    float* am = (float*)xn;                // [8][19][20] attention probs

    int tid = threadIdx.x;
    int r0 = blockIdx.x * 2;
    int wv = tid >> 6, lane = tid & 63, cl = lane & 15, g = lane >> 4;
    int c = tid;   // column 0..127

    if (tid < 2*NJ)   ord_s[tid/NJ][tid%NJ] = order[(r0 + tid/NJ)*NJ + (tid%NJ)];
    if (tid < 2*NDRP) ph_s[tid>>3][tid&7]   = ph[(r0 + (tid>>3))*NDRP + (tid&7)];
    __syncthreads();

    // ---- build x_slow (bf16) + zero pad rows ----
    for (int rr = 0; rr < 2; rr++){
        int rb = rr * 19;
        const float* xgr = xg + ((size_t)(r0 + rr)) * NJ * 128;
        xs[(rb+0)*136 + c] = f2bf(cls_tok[c]);
        #pragma unroll 1
        for (int i = 0; i < NKEEP; i++)
            xs[(rb+1+i)*136 + c] = f2bf(xgr[ord_s[rr][i]*128 + c]);
        float rep = 0.f;
        for (int i = 0; i < NDRP; i++)
            rep += ph_s[rr][i] * xgr[ord_s[rr][NKEEP+i]*128 + c];
        xs[(rb+18)*136 + c] = f2bf(rep);
    }
    for (int row = 38; row < 48; row++){ xs[row*136 + c] = 0; xn[row*136 + c] = 0; }
    __syncthreads();

    // ---- rmsnorm1 ----
    if (tid < 38){
        float ss = 0.f;
        for (int d = 0; d < 128; d++){ float v = bf2f(xs[tid*136 + d]); ss = fmaf(v, v, ss); }
        rstd[tid] = rsqrtf(ss * 0.0078125f + 1e-6f);
    }
    __syncthreads();
    {
        float w = sn1w[c];
        for (int row = 0; row < 38; row++)
            xn[row*136 + c] = f2bf(bf2f(xs[row*136 + c]) * rstd[row] * w);
    }
    __syncthreads();

    // ---- qkv GEMM (3 row-tiles x 24 col-tiles), q pre-scaled ----
    for (int job = wv; job < 72; job += 2){
        int rt = job / 24, ct = job - rt*24;
        int col = ct*16 + cl;
        bf16x8 a[4];
        #pragma unroll
        for (int ks = 0; ks < 4; ks++)
            a[ks] = *(const bf16x8*)(xn + (rt*16 + cl)*136 + ks*32 + g*8);
        f32x4 acc = {0.f, 0.f, 0.f, 0.f};
        #pragma unroll
        for (int ks = 0; ks < 4; ks++){
            bf16x8 b = *(const bf16x8*)(WinB + col*128 + ks*32 + g*8);
            acc = __builtin_amdgcn_mfma_f32_16x16x32_bf16(a[ks], b, acc, 0, 0, 0);
        }
        float bias = inb[col];
        float scl = (col < 128) ? 0.17677669529663687f : 1.0f;
        #pragma unroll
        for (int reg = 0; reg < 4; reg++){
            int row = rt*16 + g*4 + reg;
            qb[row*392 + col] = f2bf((acc[reg] + bias) * scl);
        }
    }
    __syncthreads();

    // ---- attention logits + softmax (scalar, f32 in am) ----
    for (int idx = tid; idx < 152; idx += 128){
        int jb = idx / 19, qi = idx - jb*19;
        int rr2 = jb >> 2, h = jb & 3;
        const unsigned short* qrow = qb + (rr2*19 + qi)*392 + h*32;
        float qv[32];
        #pragma unroll
        for (int d = 0; d < 32; d++) qv[d] = bf2f(qrow[d]);
        float* arow = am + (jb*19 + qi)*20;
        float mx = -1e30f;
        for (int kj = 0; kj < 19; kj++){
            const unsigned short* krow = qb + (rr2*19 + kj)*392 + 128 + h*32;
            float a = 0.f;
            #pragma unroll
            for (int d = 0; d < 32; d++) a = fmaf(qv[d], bf2f(krow[d]), a);
            arow[kj] = a; mx = fmaxf(mx, a);
        }
        float s = 0.f;
        for (int kj = 0; kj < 19; kj++){ float e = __expf(arow[kj] - mx); arow[kj] = e; s += e; }
        float inv = 1.f / s;
        for (int kj = 0; kj < 19; kj++) arow[kj] *= inv;
    }
    __syncthreads();

    // ---- next_attn scatter + PV (o into q region) ----
    if (tid < 36){
        int rr2 = tid / 18, t = tid - rr2*18;
        float v = 0.f;
        #pragma unroll
        for (int h = 0; h < 4; h++) v += am[((rr2*4 + h)*19 + 0)*20 + (1 + t)];
        v *= 0.25f;
        int r = r0 + rr2;
        if (t < NKEEP) next_attn[r*NJ + ord_s[rr2][t]] = v;
        else { for (int i = 0; i < NDRP; i++) next_attn[r*NJ + ord_s[rr2][NKEEP+i]] = v; }
    }
    {
        int h = c >> 5;
        for (int rr2 = 0; rr2 < 2; rr2++){
            for (int qi = 0; qi < 19; qi++){
                const float* arow = am + ((rr2*4 + h)*19 + qi)*20;
                float a = 0.f;
                for (int kj = 0; kj < 19; kj++)
                    a = fmaf(arow[kj], bf2f(qb[(rr2*19 + kj)*392 + 256 + c]), a);
                qb[(rr2*19 + qi)*392 + c] = f2bf(a);
            }
        }
    }
    __syncthreads();

    // ---- out-proj (attn_out -> k region; x_msa -> xs) ----
    for (int job = wv; job < 24; job += 2){
        int rt = job >> 3, ct = job & 7;
        int col = ct*16 + cl;
        bf16x8 a[4];
        #pragma unroll
        for (int ks = 0; ks < 4; ks++)
            a[ks] = *(const bf16x8*)(qb + (rt*16 + cl)*392 + ks*32 + g*8);
        f32x4 acc = {0.f, 0.f, 0.f, 0.f};
        #pragma unroll
        for (int ks = 0; ks < 4; ks++){
            bf16x8 b = *(const bf16x8*)(WoutB + col*128 + ks*32 + g*8);
            acc = __builtin_amdgcn_mfma_f32_16x16x32_bf16(a[ks], b, acc, 0, 0, 0);
        }
        float bias = outb[col];
        #pragma unroll
        for (int reg = 0; reg < 4; reg++){
            int row = rt*16 + g*4 + reg;
            float ao = acc[reg] + bias;
            qb[row*392 + 128 + col] = f2bf(ao);
            xs[row*136 + col] = f2bf(bf2f(xs[row*136 + col]) + ao);
        }
    }
    __syncthreads();

    // ---- rmsnorm2 (xs=x_msa -> xn; re-zero pads destroyed by am) ----
    if (tid < 38){
        float ss = 0.f;
        for (int d = 0; d < 128; d++){ float v = bf2f(xs[tid*136 + d]); ss = fmaf(v, v, ss); }
        rstd[tid] = rsqrtf(ss * 0.0078125f + 1e-6f);
    }
    __syncthreads();
    {
        float w = sn2w[c];
        for (int row = 0; row < 48; row++)
            xn[row*136 + c] = (row < 38) ? f2bf(bf2f(xs[row*136 + c]) * rstd[row] * w) : 0;
    }
    __syncthreads();

    // ---- ffn1 + gelu (h -> q and v regions) ----
    for (int job = wv; job < 48; job += 2){
        int rt = job >> 4, ct = job & 15;
        int col = ct*16 + cl;
        bf16x8 a[4];
        #pragma unroll
        for (int ks = 0; ks < 4; ks++)
            a[ks] = *(const bf16x8*)(xn + (rt*16 + cl)*136 + ks*32 + g*8);
        f32x4 acc = {0.f, 0.f, 0.f, 0.f};
        #pragma unroll
        for (int ks = 0; ks < 4; ks++){
            bf16x8 b = *(const bf16x8*)(F1B + col*128 + ks*32 + g*8);
            acc = __builtin_amdgcn_mfma_f32_16x16x32_bf16(a[ks], b, acc, 0, 0, 0);
        }
        float bias = f1b[col];
        int dst = (col < 128) ? col : col + 128;   // cols [128,256) -> [256,384)
        #pragma unroll
        for (int reg = 0; reg < 4; reg++){
            int row = rt*16 + g*4 + reg;
            qb[row*392 + dst] = f2bf(gelu_exact(acc[reg] + bias));
        }
    }
    __syncthreads();

    // ---- ffn2 + delta = attn_out + ffn_out ----
    for (int job = wv; job < 24; job += 2){
        int rt = job >> 3, ct = job & 7;
        int col = ct*16 + cl;
        f32x4 acc = {0.f, 0.f, 0.f, 0.f};
        #pragma unroll
        for (int ks = 0; ks < 8; ks++){
            int off = (ks < 4) ? ks*32 : ks*32 + 128;
            bf16x8 a = *(const bf16x8*)(qb + (rt*16 + cl)*392 + off + g*8);
            bf16x8 b = *(const bf16x8*)(F2B + col*256 + ks*32 + g*8);
            acc = __builtin_amdgcn_mfma_f32_16x16x32_bf16(a, b, acc, 0, 0, 0);
        }
        float bias = f2b[col];
        #pragma unroll
        for (int reg = 0; reg < 4; reg++){
            int row = rt*16 + g*4 + reg;
            if (row < 38){
                float dv = acc[reg] + bias + bf2f(qb[row*392 + 128 + col]);
                int rr2 = row / 19, tok = row - rr2*19;
                delta[((size_t)(r0 + rr2)*19 + tok)*128 + col] = f2bf(dv);
            }
        }
    }
}

// ---------------------------------------------------------------- scatter to temporal layout
__global__ void k_scatter(const float* __restrict__ xg, const unsigned short* __restrict__ delta,
                          const int* __restrict__ slot, float* __restrict__ xsp){
    int e = blockIdx.x * 256 + threadIdx.x;
    int c = e & 127; int rem = e >> 7;
    int t = rem % NTT; int nj = rem / NTT; int j = nj % NJ; int n = nj / NJ;
    int r = n * NTT + t;
    int sl = slot[r * NJ + j];
    xsp[e] = 2.0f * xg[(r * NJ + j) * 128 + c] + bf2f(delta[((size_t)r * 19 + sl) * 128 + c]);
}

// ---------------------------------------------------------------- temporal attention: MFMA, 1 wave = (nj, head)
__global__ __launch_bounds__(64) void k_tattn_mfma(
    const unsigned short* __restrict__ xb, const unsigned short* __restrict__ Wb,
    const float* __restrict__ inb, float* __restrict__ o)
{
    // LDS: q[120][40] | k[120][40] | vT[32][136] | P[16][136]  (all bf16) = 32,256 B
    __shared__ __align__(16) unsigned short smem[16128];
    unsigned short* q_s = smem;
    unsigned short* k_s = smem + 4800;
    unsigned short* vT  = smem + 9600;
    unsigned short* P_s = smem + 13952;

    int l  = threadIdx.x;
    int cl = l & 15;
    int g  = l >> 4;
    int nj = blockIdx.x >> 2;
    int h  = blockIdx.x & 3;

    for (int i = l; i < 256; i += 64) vT[(i >> 3) * 136 + 120 + (i & 7)] = 0;

    const unsigned short* xrow = xb + (size_t)nj * (NTT * 128);
    const float scale = 0.17677669529663687f;

    bf16x8 bfr[6][4];
    float bias[6];
    #pragma unroll
    for (int pc = 0; pc < 6; ++pc){
        int p = pc >> 1, s = pc & 1;
        int col = p * 128 + h * 32 + s * 16 + cl;
        bias[pc] = inb[col];
        #pragma unroll
        for (int ks = 0; ks < 4; ++ks)
            bfr[pc][ks] = *(const bf16x8*)(Wb + col * 128 + ks * 32 + g * 8);
    }

    for (int mt = 0; mt < 8; ++mt){
        bf16x8 af[4];
        #pragma unroll
        for (int ks = 0; ks < 4; ++ks)
            af[ks] = *(const bf16x8*)(xrow + (mt * 16 + cl) * 128 + ks * 32 + g * 8);
        #pragma unroll
        for (int pc = 0; pc < 6; ++pc){
            f32x4 acc = {0.f, 0.f, 0.f, 0.f};
            #pragma unroll
            for (int ks = 0; ks < 4; ++ks)
                acc = __builtin_amdgcn_mfma_f32_16x16x32_bf16(af[ks], bfr[pc][ks], acc, 0, 0, 0);
            int p = pc >> 1, s = pc & 1;
            int d = s * 16 + cl;
            #pragma unroll
            for (int reg = 0; reg < 4; ++reg){
                int t = mt * 16 + g * 4 + reg;
                if (t < NTT){
                    float v = acc[reg] + bias[pc];
                    if (p == 0)      q_s[t * 40 + d] = f2bf(v * scale);
                    else if (p == 1) k_s[t * 40 + d] = f2bf(v);
                    else             vT[d * 136 + t] = f2bf(v);
                }
            }
        }
    }
    __syncthreads();

    for (int mt = 0; mt < 8; ++mt){
        bf16x8 aq = *(const bf16x8*)(q_s + (mt * 16 + cl) * 40 + g * 8);
        f32x4 lg[8];
        #pragma unroll
        for (int jt = 0; jt < 8; ++jt){
            bf16x8 bk = *(const bf16x8*)(k_s + (jt * 16 + cl) * 40 + g * 8);
            f32x4 z = {0.f, 0.f, 0.f, 0.f};
            lg[jt] = __builtin_amdgcn_mfma_f32_16x16x32_bf16(aq, bk, z, 0, 0, 0);
        }
        if (cl >= 8){ lg[7][0] = -1e30f; lg[7][1] = -1e30f; lg[7][2] = -1e30f; lg[7][3] = -1e30f; }

        float inv[4];
        #pragma unroll
        for (int reg = 0; reg < 4; ++reg){
            float m = lg[0][reg];
            #pragma unroll
            for (int jt = 1; jt < 8; ++jt) m = fmaxf(m, lg[jt][reg]);
            m = fmaxf(m, __shfl_xor(m, 1, 64));
            m = fmaxf(m, __shfl_xor(m, 2, 64));
            m = fmaxf(m, __shfl_xor(m, 4, 64));
            m = fmaxf(m, __shfl_xor(m, 8, 64));
            float s = 0.f;
            #pragma unroll
            for (int jt = 0; jt < 8; ++jt){ float e = __expf(lg[jt][reg] - m); lg[jt][reg] = e; s += e; }
            s += __shfl_xor(s, 1, 64); s += __shfl_xor(s, 2, 64);
            s += __shfl_xor(s, 4, 64); s += __shfl_xor(s, 8, 64);
            inv[reg] = 1.f / s;
        }

        __syncthreads();
        #pragma unroll
        for (int jt = 0; jt < 8; ++jt){
            #pragma unroll
            for (int reg = 0; reg < 4; ++reg)
                P_s[(g * 4 + reg) * 136 + jt * 16 + cl] = f2bf(lg[jt][reg] * inv[reg]);
        }
        __syncthreads();

        bf16x8 ap[4];
        #pragma unroll
        for (int ks = 0; ks < 4; ++ks)
            ap[ks] = *(const bf16x8*)(P_s + cl * 136 + ks * 32 + g * 8);
        #pragma unroll
        for (int nt = 0; nt < 2; ++nt){
            f32x4 oacc = {0.f, 0.f, 0.f, 0.f};
            #pragma unroll
            for (int ks = 0; ks < 4; ++ks){
                bf16x8 bv = *(const bf16x8*)(vT + (nt * 16 + cl) * 136 + ks * 32 + g * 8);
                oacc = __builtin_amdgcn_mfma_f32_16x16x32_bf16(ap[ks], bv, oacc, 0, 0, 0);
            }
            #pragma unroll
            for (int reg = 0; reg < 4; ++reg){
                int t = mt * 16 + g * 4 + reg;
                if (t < NTT)
                    o[((size_t)nj * NTT + t) * 128 + h * 32 + nt * 16 + cl] = oacc[reg];
            }
        }
    }
}

// ---------------------------------------------------------------- temporal out-proj + residual + LN1
__global__ __launch_bounds__(128) void k_tout_ln1(
    const float* __restrict__ o, const float* __restrict__ WoutT, const float* __restrict__ ob,
    const float* __restrict__ xsp, const float* __restrict__ lnw, const float* __restrict__ lnb,
    float* __restrict__ xt1)
{
    __shared__ float so[16][128];
    __shared__ float prt[16][2][2];
    __shared__ float mv[16][2];
    int tid = threadIdx.x;
    int row0 = blockIdx.x * 16;
    for (int rr = 0; rr < 16; rr++) so[rr][tid] = o[(row0 + rr) * 128 + tid];
    __syncthreads();
    float acc[16];
    #pragma unroll
    for (int rr = 0; rr < 16; rr++) acc[rr] = 0.f;
    for (int c = 0; c < 128; c += 4){
        float w0 = WoutT[(c+0)*128+tid], w1 = WoutT[(c+1)*128+tid];
        float w2 = WoutT[(c+2)*128+tid], w3 = WoutT[(c+3)*128+tid];
        #pragma unroll
        for (int rr = 0; rr < 16; rr++){
            float4 ov = *(const float4*)&so[rr][c];
            acc[rr] = fmaf(ov.x,w0,fmaf(ov.y,w1,fmaf(ov.z,w2,fmaf(ov.w,w3,acc[rr]))));
        }
    }
    int lane = tid & 63, wv = tid >> 6;
    float bo = ob[tid];
    float y[16];
    for (int rr = 0; rr < 16; rr++) y[rr] = acc[rr] + bo + xsp[(row0 + rr) * 128 + tid];
    for (int rr = 0; rr < 16; rr++){
        float v = y[rr], v2 = v * v;
        WAVE_RED(v) WAVE_RED(v2)
        if (lane == 0){ prt[rr][wv][0] = v; prt[rr][wv][1] = v2; }
    }
    __syncthreads();
    if (tid < 16){
        float s = prt[tid][0][0] + prt[tid][1][0], s2 = prt[tid][0][1] + prt[tid][1][1];
        float m = s * 0.0078125f; float var = s2 * 0.0078125f - m * m;
        mv[tid][0] = m; mv[tid][1] = rsqrtf(var + 1e-5f);
    }
    __syncthreads();
    float lw = lnw[tid], lb = lnb[tid];
    for (int rr = 0; rr < 16; rr++)
        xt1[(row0 + rr) * 128 + tid] = (y[rr] - mv[rr][0]) * mv[rr][1] * lw + lb;
}

// ---------------------------------------------------------------- temporal FFN1 (gelu) -> bf16 hidden
__global__ __launch_bounds__(128) void k_tffn1(
    const float* __restrict__ xt1, const float* __restrict__ F1T, const float* __restrict__ f1b,
    __hip_bfloat16* __restrict__ hid)
{
    __shared__ float sx[8][128];
    int tid = threadIdx.x;
    int row0 = blockIdx.x * 8;
    for (int rr = 0; rr < 8; rr++) sx[rr][tid] = xt1[(row0 + rr) * 128 + tid];
    __syncthreads();
    float acc0[8], acc1[8];
    #pragma unroll
    for (int rr = 0; rr < 8; rr++){ acc0[rr] = 0.f; acc1[rr] = 0.f; }
    for (int c = 0; c < 128; c += 4){
        float wa0=F1T[(c+0)*256+tid],     wa1=F1T[(c+1)*256+tid];
        float wa2=F1T[(c+2)*256+tid],     wa3=F1T[(c+3)*256+tid];
        float wb0=F1T[(c+0)*256+128+tid], wb1=F1T[(c+1)*256+128+tid];
        float wb2=F1T[(c+2)*256+128+tid], wb3=F1T[(c+3)*256+128+tid];
        #pragma unroll
        for (int rr = 0; rr < 8; rr++){
            float4 xv = *(const float4*)&sx[rr][c];
            acc0[rr] = fmaf(xv.x,wa0,fmaf(xv.y,wa1,fmaf(xv.z,wa2,fmaf(xv.w,wa3,acc0[rr]))));
            acc1[rr] = fmaf(xv.x,wb0,fmaf(xv.y,wb1,fmaf(xv.z,wb2,fmaf(xv.w,wb3,acc1[rr]))));
        }
    }
    float b0 = f1b[tid], b1 = f1b[128 + tid];
    for (int rr = 0; rr < 8; rr++){
        hid[(row0 + rr) * 256 + tid]       = __float2bfloat16(gelu_exact(acc0[rr] + b0));
        hid[(row0 + rr) * 256 + 128 + tid] = __float2bfloat16(gelu_exact(acc1[rr] + b1));
    }
}

// ---------------------------------------------------------------- FFN2 + LN2 + RMSNorm + residuals -> out
__global__ __launch_bounds__(128) void k_final(
    const __hip_bfloat16* __restrict__ hid, const float* __restrict__ F2T, const float* __restrict__ f2b,
    const float* __restrict__ xt1, const float* __restrict__ ln2w, const float* __restrict__ ln2b,
    const float* __restrict__ tnw, const float* __restrict__ xsp, const float* __restrict__ x,
    float* __restrict__ out)
{
    __shared__ float sh[8][256];
    __shared__ float prt[8][2][2];
    __shared__ float mv[8][2];
    __shared__ float pr2[8][2];
    __shared__ float sr2[8];
    int tid = threadIdx.x;
    int row0 = blockIdx.x * 8;
    {
        float* shf = &sh[0][0];
        for (int i = tid; i < 8 * 256; i += 128) shf[i] = __bfloat162float(hid[row0 * 256 + i]);
    }
    __syncthreads();
    float acc[8];
    #pragma unroll
    for (int rr = 0; rr < 8; rr++) acc[rr] = 0.f;
    for (int kk = 0; kk < 256; kk += 4){
        float w0 = F2T[(kk+0)*128+tid], w1 = F2T[(kk+1)*128+tid];
        float w2 = F2T[(kk+2)*128+tid], w3 = F2T[(kk+3)*128+tid];
        #pragma unroll
        for (int rr = 0; rr < 8; rr++){
            float4 hv = *(const float4*)&sh[rr][kk];
            acc[rr] = fmaf(hv.x,w0,fmaf(hv.y,w1,fmaf(hv.z,w2,fmaf(hv.w,w3,acc[rr]))));
        }
    }
    int lane = tid & 63, wv = tid >> 6;
    float b2 = f2b[tid];
    float y[8];
    for (int rr = 0; rr < 8; rr++) y[rr] = acc[rr] + b2 + xt1[(row0 + rr) * 128 + tid];
    for (int rr = 0; rr < 8; rr++){
        float v = y[rr], v2 = v * v;
        WAVE_RED(v) WAVE_RED(v2)
        if (lane == 0){ prt[rr][wv][0] = v; prt[rr][wv][1] = v2; }
    }
    __syncthreads();
    if (tid < 8){
        float s = prt[tid][0][0] + prt[tid][1][0], s2 = prt[tid][0][1] + prt[tid][1][1];
        float m = s * 0.0078125f; float var = s2 * 0.0078125f - m * m;
        mv[tid][0] = m; mv[tid][1] = rsqrtf(var + 1e-5f);
    }
    __syncthreads();
    float z[8];
    float lw = ln2w[tid], lb = ln2b[tid];
    for (int rr = 0; rr < 8; rr++) z[rr] = (y[rr] - mv[rr][0]) * mv[rr][1] * lw + lb;
    for (int rr = 0; rr < 8; rr++){
        float v = z[rr] * z[rr];
        WAVE_RED(v)
        if (lane == 0) pr2[rr][wv] = v;
    }
    __syncthreads();
    if (tid < 8) sr2[tid] = rsqrtf((pr2[tid][0] + pr2[tid][1]) * 0.0078125f + 1e-6f);
    __syncthreads();
    float tw = tnw[tid];
    for (int rr = 0; rr < 8; rr++){
        int row = row0 + rr;
        int t = row % NTT; int nj = row / NTT; int j = nj % NJ; int n = nj / NJ;
        int xi = ((n * NTT + t) * NJ + j) * 128 + tid;
        out[xi] = z[rr] * sr2[rr] * tw + xsp[row * 128 + tid] + x[xi];
    }
}

// ================================================================ launch
extern "C" void kernel_launch(void* const* d_in, const int* in_sizes, int n_in,
                              void* d_out, int out_size, void* d_ws, size_t ws_size,
                              hipStream_t stream) {
    (void)in_sizes; (void)n_in; (void)out_size;
    const float* x      = (const float*)d_in[0];
    const float* sc     = (const float*)d_in[1];
    const float* gcnw   = (const float*)d_in[2];
    const float* gnw    = (const float*)d_in[3];
    const float* cls    = (const float*)d_in[4];
    const float* sn1    = (const float*)d_in[5];
    const float* sn2    = (const float*)d_in[6];
    const float* s_in_w = (const float*)d_in[7];
    const float* s_in_b = (const float*)d_in[8];
    const float* s_out_w= (const float*)d_in[9];
    const float* s_out_b= (const float*)d_in[10];
    const float* s_f1w  = (const float*)d_in[11];
    const float* s_f1b  = (const float*)d_in[12];
    const float* s_f2w  = (const float*)d_in[13];
    const float* s_f2b  = (const float*)d_in[14];
    const float* t_in_w = (const float*)d_in[15];
    const float* t_in_b = (const float*)d_in[16];
    const float* t_out_w= (const float*)d_in[17];
    const float* t_out_b= (const float*)d_in[18];
    const float* t_ln1w = (const float*)d_in[19];
    const float* t_ln1b = (const float*)d_in[20];
    const float* t_ln2w = (const float*)d_in[21];
    const float* t_ln2b = (const float*)d_in[22];
    const float* t_f1w  = (const float*)d_in[23];
    const float* t_f1b  = (const float*)d_in[24];
    const float* t_f2w  = (const float*)d_in[25];
    const float* t_f2b  = (const float*)d_in[26];
    const float* tnw    = (const float*)d_in[27];

    char* ws = (char*)d_ws;
    const size_t SZ_BIG = 98304000;                 // 192000*128*4
    float* R1 = (float*)ws;                         // x_gcn -> o -> hidden(bf16)
    float* R2 = (float*)(ws + SZ_BIG);              // x_sp (n,j,t,c)
    float* R3 = (float*)(ws + 2 * SZ_BIG);          // delta(bf16) -> xb(bf16) -> xt1
    char* p = ws + 3 * SZ_BIG;
    int*   ORD  = (int*)p;   p += 768000;
    int*   SLOT = (int*)p;   p += 768000;
    float* PH   = (float*)p; p += 245760;
    char*  WTS  = p;         p += 524288;            // spatial bf16 weights
    float* WTT  = (float*)p; p += 524288;            // temporal fp32 transposed weights
    unsigned short* WB = (unsigned short*)p; p += 98304;   // t_in_w bf16 [384][128]
    if (ws_size < (size_t)(p - ws)) return;

    unsigned short* WinB  = (unsigned short*)WTS;           // [384][128]
    unsigned short* WoutB = WinB  + 49152;                  // [128][128]
    unsigned short* F1B   = WoutB + 16384;                  // [256][128]
    unsigned short* F2B   = F1B   + 32768;                  // [128][256]
    float* WoutT_t = WTT + 49152;
    float* F1T_t   = WTT + 65536;
    float* F2T_t   = WTT + 98304;
    unsigned short* DLT = (unsigned short*)R3;      // delta bf16 [NTR*19][128]
    unsigned short* XB  = (unsigned short*)R3;      // bf16 x for temporal attn (overwrites delta)

    float* out0 = (float*)d_out;
    float* next_attn = out0 + 24576000;

    k_transpose<<< 64, 256, 0, stream>>>(t_out_w, WoutT_t,128, 128);
    k_transpose<<<128, 256, 0, stream>>>(t_f1w,   F1T_t,  256, 128);
    k_transpose<<<128, 256, 0, stream>>>(t_f2w,   F2T_t,  128, 256);
    k_wcast<<<48, 256, 0, stream>>>(s_in_w,  WinB,  12288);
    k_wcast<<<16, 256, 0, stream>>>(s_out_w, WoutB, 4096);
    k_wcast<<<32, 256, 0, stream>>>(s_f1w,   F1B,   8192);
    k_wcast<<<32, 256, 0, stream>>>(s_f2w,   F2B,   8192);
    k_wcast<<<48, 256, 0, stream>>>(t_in_w,  WB,    12288);

    k_gcn<<<12000, 128, 0, stream>>>(x, gcnw, gnw, R1);
    k_select<<<30, 256, 0, stream>>>(sc, ORD, SLOT, PH);
    k_spatial_mfma<<<3840, 128, 0, stream>>>(R1, ORD, PH, cls, sn1, sn2,
                                             WinB, s_in_b, WoutB, s_out_b,
                                             F1B, s_f1b, F2B, s_f2b,
                                             DLT, next_attn);
    k_scatter<<<96000, 256, 0, stream>>>(R1, DLT, SLOT, R2);
    k_xcast<<<24000, 256, 0, stream>>>(R2, XB);                            // delta dead; R3 -> xb
    k_tattn_mfma<<<6400, 64, 0, stream>>>(XB, WB, t_in_b, R1);             // o -> R1
    k_tout_ln1<<<12000, 128, 0, stream>>>(R1, WoutT_t, t_out_b, R2,
                                          t_ln1w, t_ln1b, R3);             // xt1 -> R3 (xb dead)
    k_tffn1<<<24000, 128, 0, stream>>>(R3, F1T_t, t_f1b, (__hip_bfloat16*)R1);
    k_final<<<24000, 128, 0, stream>>>((const __hip_bfloat16*)R1, F2T_t, t_f2b,
                                       R3, t_ln2w, t_ln2b, tnw, R2, x, out0);
}

// Round 4
// 1239.638 us; speedup vs baseline: 3.8314x; 1.4448x over previous
//
#include <hip/hip_runtime.h>
#include <hip/hip_bf16.h>
#include <math.h>

// Problem constants
#define NTR   7680      // N*T
#define NJ    25
#define NKEEP 17
#define NDRP  8
#define NL    19
#define NROW  192000    // NT*J == N*J*T
#define NTT   120
#define RSP   24        // padded rows per r in spatial block

typedef __attribute__((ext_vector_type(8))) short bf16x8;
typedef __attribute__((ext_vector_type(4))) float f32x4;

__device__ __forceinline__ float gelu_exact(float v){
    return 0.5f * v * (1.0f + erff(v * 0.70710678118654752440f));
}
__device__ __forceinline__ unsigned short f2bf(float v){
    union { float f; unsigned u; } a; a.f = v;
    unsigned r = a.u + 0x7FFF + ((a.u >> 16) & 1);   // RNE
    return (unsigned short)(r >> 16);
}
__device__ __forceinline__ float bf2f(unsigned short u){
    union { unsigned u; float f; } a; a.u = ((unsigned)u) << 16; return a.f;
}

// ---------------------------------------------------------------- weight casts
__global__ void k_wcast(const float* __restrict__ in, unsigned short* __restrict__ out, int n4){
    int i = blockIdx.x * 256 + threadIdx.x;
    if (i < n4){
        float4 v = *(const float4*)(in + i * 4);
        ushort4 o; o.x = f2bf(v.x); o.y = f2bf(v.y); o.z = f2bf(v.z); o.w = f2bf(v.w);
        *(ushort4*)(out + i * 4) = o;
    }
}
// gcn: W[c][d] -> W^T bf16 [d][c]
__global__ void k_tcast(const float* __restrict__ in, unsigned short* __restrict__ out){
    int i = blockIdx.x * 256 + threadIdx.x;   // 16384
    int d = i >> 7, c = i & 127;
    out[d * 128 + c] = f2bf(in[c * 128 + d]);
}

// ---------------------------------------------------------------- GCN + RMSNorm (MFMA)
__global__ __launch_bounds__(256) void k_gcn_mfma(
    const float* __restrict__ x, const unsigned short* __restrict__ GWt,
    const float* __restrict__ gnw, float* __restrict__ xg)
{
    __shared__ __align__(16) unsigned short xb[64 * 136];
    __shared__ __align__(16) float yf[64 * 132];
    __shared__ float rstd[64];
    int tid = threadIdx.x, wv = tid >> 6, lane = tid & 63, cl = lane & 15, g = lane >> 4;
    size_t row0 = (size_t)blockIdx.x * 64;

    const float4* x4 = (const float4*)(x + row0 * 128);
    for (int i = tid; i < 2048; i += 256){
        int row = i >> 5, ch = i & 31;
        float4 v = x4[row * 32 + ch];
        ushort4 o; o.x = f2bf(v.x); o.y = f2bf(v.y); o.z = f2bf(v.z); o.w = f2bf(v.w);
        *(ushort4*)(xb + row * 136 + ch * 4) = o;
    }
    __syncthreads();
    for (int job = wv; job < 32; job += 4){
        int rt = job >> 3, ct = job & 7, col = ct * 16 + cl;
        f32x4 acc = {0.f, 0.f, 0.f, 0.f};
        #pragma unroll
        for (int ks = 0; ks < 4; ks++){
            bf16x8 a = *(const bf16x8*)(xb + (rt*16 + cl)*136 + ks*32 + g*8);
            bf16x8 b = *(const bf16x8*)(GWt + col*128 + ks*32 + g*8);
            acc = __builtin_amdgcn_mfma_f32_16x16x32_bf16(a, b, acc, 0, 0, 0);
        }
        #pragma unroll
        for (int reg = 0; reg < 4; reg++)
            yf[(rt*16 + g*4 + reg)*132 + col] = acc[reg];
    }
    __syncthreads();
    {
        int grp = tid >> 2, sub = tid & 3;
        float ss = 0.f;
        const float4* yr = (const float4*)(yf + grp*132 + sub*32);
        #pragma unroll
        for (int j = 0; j < 8; j++){ float4 v = yr[j]; ss += v.x*v.x + v.y*v.y + v.z*v.z + v.w*v.w; }
        ss += __shfl_xor(ss, 1, 64); ss += __shfl_xor(ss, 2, 64);
        if (sub == 0) rstd[grp] = rsqrtf(ss * 0.0078125f + 1e-6f);
    }
    __syncthreads();
    {
        int c = tid & 127; float w = gnw[c];
        for (int row = tid >> 7; row < 64; row += 2)
            xg[(row0 + row)*128 + c] = yf[row*132 + c] * rstd[row] * w;
    }
}

// ---------------------------------------------------------------- per-row token selection
__global__ void k_select(const float* __restrict__ sc, int* __restrict__ order,
                         int* __restrict__ slot, float* __restrict__ ph){
    int r = blockIdx.x * blockDim.x + threadIdx.x;
    if (r >= NTR) return;
    float s[NJ]; int id[NJ];
    for (int j = 0; j < NJ; j++){ s[j] = sc[r * NJ + j]; id[j] = j; }
    for (int m = 1; m < NJ; m++){
        float sv = s[m]; int iv = id[m]; int p = m;
        while (p > 0 && s[p-1] < sv){ s[p] = s[p-1]; id[p] = id[p-1]; p--; }
        s[p] = sv; id[p] = iv;
    }
    for (int j = 0; j < NJ; j++) order[r * NJ + j] = id[j];
    for (int i = 0; i < NKEEP; i++)  slot[r * NJ + id[i]] = 1 + i;
    for (int i = NKEEP; i < NJ; i++) slot[r * NJ + id[i]] = 18;
    float m8 = s[NKEEP];
    float e[NDRP]; float sum = 0.f;
    for (int i = 0; i < NDRP; i++){ e[i] = expf(s[NKEEP + i] - m8); sum += e[i]; }
    float inv = 1.f / sum;
    for (int i = 0; i < NDRP; i++) ph[r * NDRP + i] = e[i] * inv;
}

// ---------------------------------------------------------------- spatial transformer v2: 256 thr, all-MFMA
// sm u16 layout: xs[48][136] | U1: xn[48][136] / P[8][32][40] | qk[48][264] | U2: vT[8][32][40] / ao[48][136]
__global__ __launch_bounds__(256) void k_spatial2(
    const float* __restrict__ xg, const int* __restrict__ order, const float* __restrict__ ph,
    const float* __restrict__ cls_tok, const float* __restrict__ sn1w, const float* __restrict__ sn2w,
    const unsigned short* __restrict__ WinB, const float* __restrict__ inb,
    const unsigned short* __restrict__ WoutB, const float* __restrict__ outb,
    const unsigned short* __restrict__ F1B, const float* __restrict__ f1b,
    const unsigned short* __restrict__ F2B, const float* __restrict__ f2b,
    unsigned short* __restrict__ delta, float* __restrict__ next_attn)
{
    __shared__ __align__(16) unsigned short sm[39680];
    __shared__ float rstd[48];
    __shared__ float clsp[8][20];
    __shared__ int   ord_s[2][NJ];
    __shared__ float ph_s[2][NDRP];
    unsigned short* xs = sm;             // [48][136]
    unsigned short* xn = sm + 6528;      // [48][136]
    unsigned short* Pb = sm + 6528;      // [8][32][40] overlays xn
    unsigned short* qk = sm + 16768;     // [48][264]
    unsigned short* vT = sm + 29440;     // [8][32][40]
    unsigned short* ao = sm + 29440;     // [48][136] overlays vT

    int tid = threadIdx.x;
    int r0 = blockIdx.x * 2;
    int wv = tid >> 6, lane = tid & 63, cl = lane & 15, g = lane >> 4;

    if (tid < 2*NJ)   ord_s[tid/NJ][tid%NJ] = order[(r0 + tid/NJ)*NJ + tid%NJ];
    if (tid < 2*NDRP) ph_s[tid>>3][tid&7]   = ph[(r0 + (tid>>3))*NDRP + (tid&7)];
    for (int i = tid; i < 10240; i += 256) vT[i] = 0;     // zero U2 (pad keys must be 0)
    __syncthreads();

    // ---- build x_slow ----
    {
        int rr = tid >> 7, c = tid & 127;
        const float* xgr = xg + (size_t)(r0 + rr) * NJ * 128;
        int rb = rr * RSP;
        xs[rb*136 + c] = f2bf(cls_tok[c]);
        #pragma unroll 1
        for (int i = 0; i < NKEEP; i++)
            xs[(rb+1+i)*136 + c] = f2bf(xgr[ord_s[rr][i]*128 + c]);
        float rep = 0.f;
        for (int i = 0; i < NDRP; i++)
            rep += ph_s[rr][i] * xgr[ord_s[rr][NKEEP+i]*128 + c];
        xs[(rb+18)*136 + c] = f2bf(rep);
        for (int t2 = 19; t2 < RSP; t2++) xs[(rb+t2)*136 + c] = 0;
    }
    __syncthreads();

    // ---- rmsnorm1 ----
    {
        int grp = tid >> 2, sub = tid & 3;
        if (grp < 48){
            float ss = 0.f;
            #pragma unroll
            for (int j = 0; j < 4; j++){
                bf16x8 v = *(const bf16x8*)(xs + grp*136 + sub*32 + j*8);
                #pragma unroll
                for (int e = 0; e < 8; e++){ float f = bf2f((unsigned short)v[e]); ss = fmaf(f, f, ss); }
            }
            ss += __shfl_xor(ss, 1, 64); ss += __shfl_xor(ss, 2, 64);
            if (sub == 0) rstd[grp] = rsqrtf(ss * 0.0078125f + 1e-6f);
        }
    }
    __syncthreads();
    {
        int c = tid & 127; float w = sn1w[c];
        for (int row = tid >> 7; row < 48; row += 2)
            xn[row*136 + c] = f2bf(bf2f(xs[row*136 + c]) * rstd[row] * w);
    }
    __syncthreads();

    // ---- qkv GEMM: q (scaled) + k -> qk, v -> vT ----
    for (int job = wv; job < 72; job += 4){
        int rt = job / 24, ct = job - rt*24, col = ct*16 + cl;
        f32x4 acc = {0.f, 0.f, 0.f, 0.f};
        #pragma unroll
        for (int ks = 0; ks < 4; ks++){
            bf16x8 a = *(const bf16x8*)(xn + (rt*16 + cl)*136 + ks*32 + g*8);
            bf16x8 b = *(const bf16x8*)(WinB + col*128 + ks*32 + g*8);
            acc = __builtin_amdgcn_mfma_f32_16x16x32_bf16(a, b, acc, 0, 0, 0);
        }
        float bias = inb[col];
        if (col < 128){
            #pragma unroll
            for (int reg = 0; reg < 4; reg++){
                int row = rt*16 + g*4 + reg;
                qk[row*264 + col] = f2bf((acc[reg] + bias) * 0.17677669529663687f);
            }
        } else if (col < 256){
            #pragma unroll
            for (int reg = 0; reg < 4; reg++){
                int row = rt*16 + g*4 + reg;
                qk[row*264 + col] = f2bf(acc[reg] + bias);
            }
        } else {
            int h = (col - 256) >> 5, d = (col - 256) & 31;
            #pragma unroll
            for (int reg = 0; reg < 4; reg++){
                int row = rt*16 + g*4 + reg;
                int rr = row >= RSP; int key = row - rr*RSP;
                vT[(rr*4 + h)*1280 + d*40 + key] = f2bf(acc[reg] + bias);
            }
        }
    }
    __syncthreads();

    // ---- attention: 2 (rr,h) pairs per wave, MFMA QK^T + reg softmax + MFMA PV ----
    for (int s = 0; s < 2; s++){
        int qh = wv*2 + s;
        int rr = qh >> 2, h = qh & 3;
        bf16x8 aq[2];
        #pragma unroll
        for (int qt = 0; qt < 2; qt++)
            aq[qt] = *(const bf16x8*)(qk + (rr*RSP + qt*16 + cl)*264 + h*32 + g*8);
        f32x4 lg[2][2];
        #pragma unroll
        for (int kt = 0; kt < 2; kt++){
            bf16x8 bk = *(const bf16x8*)(qk + (rr*RSP + kt*16 + cl)*264 + 128 + h*32 + g*8);
            f32x4 z = {0.f, 0.f, 0.f, 0.f};
            lg[0][kt] = __builtin_amdgcn_mfma_f32_16x16x32_bf16(aq[0], bk, z, 0, 0, 0);
            lg[1][kt] = __builtin_amdgcn_mfma_f32_16x16x32_bf16(aq[1], bk, z, 0, 0, 0);
        }
        #pragma unroll
        for (int qt = 0; qt < 2; qt++){
            #pragma unroll
            for (int reg = 0; reg < 4; reg++){
                float l0 = lg[qt][0][reg];
                float l1 = (cl >= 3) ? -1e30f : lg[qt][1][reg];
                float m = fmaxf(l0, l1);
                m = fmaxf(m, __shfl_xor(m, 1, 64));
                m = fmaxf(m, __shfl_xor(m, 2, 64));
                m = fmaxf(m, __shfl_xor(m, 4, 64));
                m = fmaxf(m, __shfl_xor(m, 8, 64));
                float e0 = __expf(l0 - m), e1 = __expf(l1 - m);
                float ssum = e0 + e1;
                ssum += __shfl_xor(ssum, 1, 64); ssum += __shfl_xor(ssum, 2, 64);
                ssum += __shfl_xor(ssum, 4, 64); ssum += __shfl_xor(ssum, 8, 64);
                float inv = 1.f / ssum;
                e0 *= inv; e1 *= inv;
                int q = qt*16 + g*4 + reg;
                Pb[qh*1280 + q*40 + cl]      = f2bf(e0);
                Pb[qh*1280 + q*40 + 16 + cl] = f2bf(e1);
                if (qt == 0 && g == 0 && reg == 0){
                    clsp[qh][cl] = e0;
                    if (cl < 4) clsp[qh][16 + cl] = e1;
                }
            }
        }
        __syncthreads();    // P visible (also aligns all waves)
        bf16x8 ap[2];
        #pragma unroll
        for (int qt = 0; qt < 2; qt++)
            ap[qt] = *(const bf16x8*)(Pb + qh*1280 + (qt*16 + cl)*40 + g*8);
        #pragma unroll
        for (int dt = 0; dt < 2; dt++){
            bf16x8 bv = *(const bf16x8*)(vT + qh*1280 + (dt*16 + cl)*40 + g*8);
            #pragma unroll
            for (int qt = 0; qt < 2; qt++){
                f32x4 z = {0.f, 0.f, 0.f, 0.f};
                f32x4 oa = __builtin_amdgcn_mfma_f32_16x16x32_bf16(ap[qt], bv, z, 0, 0, 0);
                #pragma unroll
                for (int reg = 0; reg < 4; reg++){
                    int q = qt*16 + g*4 + reg;
                    if (q < 19)
                        qk[(rr*RSP + q)*264 + h*32 + dt*16 + cl] = f2bf(oa[reg]);
                    else if (q < RSP)
                        qk[(rr*RSP + q)*264 + h*32 + dt*16 + cl] = 0;
                }
            }
        }
        __syncthreads();
    }

    // ---- next_attn (f32 probs from clsp) ----
    if (tid < 36){
        int rr2 = tid / 18, t = tid - rr2*18;
        float v = 0.25f * (clsp[rr2*4+0][1+t] + clsp[rr2*4+1][1+t] +
                           clsp[rr2*4+2][1+t] + clsp[rr2*4+3][1+t]);
        int r = r0 + rr2;
        if (t < NKEEP) next_attn[r*NJ + ord_s[rr2][t]] = v;
        else { for (int i = 0; i < NDRP; i++) next_attn[r*NJ + ord_s[rr2][NKEEP+i]] = v; }
    }

    // ---- out-proj: attn_out -> ao, x_msa -> xs ----
    for (int job = wv; job < 24; job += 4){
        int rt = job >> 3, ct = job & 7, col = ct*16 + cl;
        f32x4 acc = {0.f, 0.f, 0.f, 0.f};
        #pragma unroll
        for (int ks = 0; ks < 4; ks++){
            bf16x8 a = *(const bf16x8*)(qk + (rt*16 + cl)*264 + ks*32 + g*8);
            bf16x8 b = *(const bf16x8*)(WoutB + col*128 + ks*32 + g*8);
            acc = __builtin_amdgcn_mfma_f32_16x16x32_bf16(a, b, acc, 0, 0, 0);
        }
        float bias = outb[col];
        #pragma unroll
        for (int reg = 0; reg < 4; reg++){
            int row = rt*16 + g*4 + reg;
            float v = acc[reg] + bias;
            ao[row*136 + col] = f2bf(v);
            xs[row*136 + col] = f2bf(bf2f(xs[row*136 + col]) + v);
        }
    }
    __syncthreads();

    // ---- rmsnorm2 ----
    {
        int grp = tid >> 2, sub = tid & 3;
        if (grp < 48){
            float ss = 0.f;
            #pragma unroll
            for (int j = 0; j < 4; j++){
                bf16x8 v = *(const bf16x8*)(xs + grp*136 + sub*32 + j*8);
                #pragma unroll
                for (int e = 0; e < 8; e++){ float f = bf2f((unsigned short)v[e]); ss = fmaf(f, f, ss); }
            }
            ss += __shfl_xor(ss, 1, 64); ss += __shfl_xor(ss, 2, 64);
            if (sub == 0) rstd[grp] = rsqrtf(ss * 0.0078125f + 1e-6f);
        }
    }
    __syncthreads();
    {
        int c = tid & 127; float w = sn2w[c];
        for (int row = tid >> 7; row < 48; row += 2)
            xn[row*136 + c] = f2bf(bf2f(xs[row*136 + c]) * rstd[row] * w);
    }
    __syncthreads();

    // ---- ffn1 + gelu -> qk cols 0..255 ----
    for (int job = wv; job < 48; job += 4){
        int rt = job >> 4, ct = job & 15, col = ct*16 + cl;
        f32x4 acc = {0.f, 0.f, 0.f, 0.f};
        #pragma unroll
        for (int ks = 0; ks < 4; ks++){
            bf16x8 a = *(const bf16x8*)(xn + (rt*16 + cl)*136 + ks*32 + g*8);
            bf16x8 b = *(const bf16x8*)(F1B + col*128 + ks*32 + g*8);
            acc = __builtin_amdgcn_mfma_f32_16x16x32_bf16(a, b, acc, 0, 0, 0);
        }
        float bias = f1b[col];
        #pragma unroll
        for (int reg = 0; reg < 4; reg++){
            int row = rt*16 + g*4 + reg;
            qk[row*264 + col] = f2bf(gelu_exact(acc[reg] + bias));
        }
    }
    __syncthreads();

    // ---- ffn2 + delta ----
    for (int job = wv; job < 24; job += 4){
        int rt = job >> 3, ct = job & 7, col = ct*16 + cl;
        f32x4 acc = {0.f, 0.f, 0.f, 0.f};
        #pragma unroll
        for (int ks = 0; ks < 8; ks++){
            bf16x8 a = *(const bf16x8*)(qk + (rt*16 + cl)*264 + ks*32 + g*8);
            bf16x8 b = *(const bf16x8*)(F2B + col*256 + ks*32 + g*8);
            acc = __builtin_amdgcn_mfma_f32_16x16x32_bf16(a, b, acc, 0, 0, 0);
        }
        float bias = f2b[col];
        #pragma unroll
        for (int reg = 0; reg < 4; reg++){
            int row = rt*16 + g*4 + reg;
            int rr = row >= RSP; int tok = row - rr*RSP;
            if (tok < 19){
                float dv = acc[reg] + bias + bf2f(ao[row*136 + col]);
                delta[((size_t)(r0 + rr)*19 + tok)*128 + col] = f2bf(dv);
            }
        }
    }
}

// ---------------------------------------------------------------- scatter + bf16 cast fused
__global__ void k_scatter2(const float* __restrict__ xg, const unsigned short* __restrict__ delta,
                           const int* __restrict__ slot, float* __restrict__ xsp,
                           unsigned short* __restrict__ xb){
    int i = blockIdx.x * 256 + threadIdx.x;   // 6,144,000 quads
    int e = i * 4;
    int c = e & 127; int rem = e >> 7;
    int t = rem % NTT; int nj = rem / NTT; int j = nj % NJ; int n = nj / NJ;
    int r = n * NTT + t;
    int sl = slot[r * NJ + j];
    float4 xv = *(const float4*)(xg + ((size_t)r * NJ + j) * 128 + c);
    ushort4 dv = *(const ushort4*)(delta + ((size_t)r * 19 + sl) * 128 + c);
    float4 o;
    o.x = 2.f * xv.x + bf2f(dv.x);
    o.y = 2.f * xv.y + bf2f(dv.y);
    o.z = 2.f * xv.z + bf2f(dv.z);
    o.w = 2.f * xv.w + bf2f(dv.w);
    *(float4*)(xsp + e) = o;
    ushort4 ob; ob.x = f2bf(o.x); ob.y = f2bf(o.y); ob.z = f2bf(o.z); ob.w = f2bf(o.w);
    *(ushort4*)(xb + e) = ob;
}

// ---------------------------------------------------------------- temporal attention: MFMA, 1 wave = (nj, head)
__global__ __launch_bounds__(64) void k_tattn_mfma(
    const unsigned short* __restrict__ xb, const unsigned short* __restrict__ Wb,
    const float* __restrict__ inb, float* __restrict__ o)
{
    __shared__ __align__(16) unsigned short smem[16128];
    unsigned short* q_s = smem;
    unsigned short* k_s = smem + 4800;
    unsigned short* vT  = smem + 9600;
    unsigned short* P_s = smem + 13952;

    int l  = threadIdx.x;
    int cl = l & 15;
    int g  = l >> 4;
    int nj = blockIdx.x >> 2;
    int h  = blockIdx.x & 3;

    for (int i = l; i < 256; i += 64) vT[(i >> 3) * 136 + 120 + (i & 7)] = 0;

    const unsigned short* xrow = xb + (size_t)nj * (NTT * 128);
    const float scale = 0.17677669529663687f;

    bf16x8 bfr[6][4];
    float bias[6];
    #pragma unroll
    for (int pc = 0; pc < 6; ++pc){
        int p = pc >> 1, s = pc & 1;
        int col = p * 128 + h * 32 + s * 16 + cl;
        bias[pc] = inb[col];
        #pragma unroll
        for (int ks = 0; ks < 4; ++ks)
            bfr[pc][ks] = *(const bf16x8*)(Wb + col * 128 + ks * 32 + g * 8);
    }

    for (int mt = 0; mt < 8; ++mt){
        bf16x8 af[4];
        #pragma unroll
        for (int ks = 0; ks < 4; ++ks)
            af[ks] = *(const bf16x8*)(xrow + (mt * 16 + cl) * 128 + ks * 32 + g * 8);
        #pragma unroll
        for (int pc = 0; pc < 6; ++pc){
            f32x4 acc = {0.f, 0.f, 0.f, 0.f};
            #pragma unroll
            for (int ks = 0; ks < 4; ++ks)
                acc = __builtin_amdgcn_mfma_f32_16x16x32_bf16(af[ks], bfr[pc][ks], acc, 0, 0, 0);
            int p = pc >> 1, s = pc & 1;
            int d = s * 16 + cl;
            #pragma unroll
            for (int reg = 0; reg < 4; ++reg){
                int t = mt * 16 + g * 4 + reg;
                if (t < NTT){
                    float v = acc[reg] + bias[pc];
                    if (p == 0)      q_s[t * 40 + d] = f2bf(v * scale);
                    else if (p == 1) k_s[t * 40 + d] = f2bf(v);
                    else             vT[d * 136 + t] = f2bf(v);
                }
            }
        }
    }
    __syncthreads();

    for (int mt = 0; mt < 8; ++mt){
        bf16x8 aq = *(const bf16x8*)(q_s + (mt * 16 + cl) * 40 + g * 8);
        f32x4 lg[8];
        #pragma unroll
        for (int jt = 0; jt < 8; ++jt){
            bf16x8 bk = *(const bf16x8*)(k_s + (jt * 16 + cl) * 40 + g * 8);
            f32x4 z = {0.f, 0.f, 0.f, 0.f};
            lg[jt] = __builtin_amdgcn_mfma_f32_16x16x32_bf16(aq, bk, z, 0, 0, 0);
        }
        if (cl >= 8){ lg[7][0] = -1e30f; lg[7][1] = -1e30f; lg[7][2] = -1e30f; lg[7][3] = -1e30f; }

        float inv[4];
        #pragma unroll
        for (int reg = 0; reg < 4; ++reg){
            float m = lg[0][reg];
            #pragma unroll
            for (int jt = 1; jt < 8; ++jt) m = fmaxf(m, lg[jt][reg]);
            m = fmaxf(m, __shfl_xor(m, 1, 64));
            m = fmaxf(m, __shfl_xor(m, 2, 64));
            m = fmaxf(m, __shfl_xor(m, 4, 64));
            m = fmaxf(m, __shfl_xor(m, 8, 64));
            float s = 0.f;
            #pragma unroll
            for (int jt = 0; jt < 8; ++jt){ float e = __expf(lg[jt][reg] - m); lg[jt][reg] = e; s += e; }
            s += __shfl_xor(s, 1, 64); s += __shfl_xor(s, 2, 64);
            s += __shfl_xor(s, 4, 64); s += __shfl_xor(s, 8, 64);
            inv[reg] = 1.f / s;
        }

        __syncthreads();
        #pragma unroll
        for (int jt = 0; jt < 8; ++jt){
            #pragma unroll
            for (int reg = 0; reg < 4; ++reg)
                P_s[(g * 4 + reg) * 136 + jt * 16 + cl] = f2bf(lg[jt][reg] * inv[reg]);
        }
        __syncthreads();

        bf16x8 ap[4];
        #pragma unroll
        for (int ks = 0; ks < 4; ++ks)
            ap[ks] = *(const bf16x8*)(P_s + cl * 136 + ks * 32 + g * 8);
        #pragma unroll
        for (int nt = 0; nt < 2; ++nt){
            f32x4 oacc = {0.f, 0.f, 0.f, 0.f};
            #pragma unroll
            for (int ks = 0; ks < 4; ++ks){
                bf16x8 bv = *(const bf16x8*)(vT + (nt * 16 + cl) * 136 + ks * 32 + g * 8);
                oacc = __builtin_amdgcn_mfma_f32_16x16x32_bf16(ap[ks], bv, oacc, 0, 0, 0);
            }
            #pragma unroll
            for (int reg = 0; reg < 4; ++reg){
                int t = mt * 16 + g * 4 + reg;
                if (t < NTT)
                    o[((size_t)nj * NTT + t) * 128 + h * 32 + nt * 16 + cl] = oacc[reg];
            }
        }
    }
}

// ---------------------------------------------------------------- temporal out-proj + residual + LN1 (MFMA)
__global__ __launch_bounds__(256) void k_tout_mfma(
    const float* __restrict__ o, const unsigned short* __restrict__ WoB,
    const float* __restrict__ ob, const float* __restrict__ xsp,
    const float* __restrict__ lnw, const float* __restrict__ lnb,
    float* __restrict__ xt1)
{
    __shared__ __align__(16) unsigned short xbuf[64 * 136];
    __shared__ __align__(16) float yf[64 * 132];
    __shared__ float mrow[64], vrow[64];
    int tid = threadIdx.x, wv = tid >> 6, lane = tid & 63, cl = lane & 15, g = lane >> 4;
    size_t row0 = (size_t)blockIdx.x * 64;

    const float4* x4 = (const float4*)(o + row0 * 128);
    for (int i = tid; i < 2048; i += 256){
        int row = i >> 5, ch = i & 31;
        float4 v = x4[row * 32 + ch];
        ushort4 u; u.x = f2bf(v.x); u.y = f2bf(v.y); u.z = f2bf(v.z); u.w = f2bf(v.w);
        *(ushort4*)(xbuf + row * 136 + ch * 4) = u;
    }
    __syncthreads();
    for (int job = wv; job < 32; job += 4){
        int rt = job >> 3, ct = job & 7, col = ct * 16 + cl;
        f32x4 acc = {0.f, 0.f, 0.f, 0.f};
        #pragma unroll
        for (int ks = 0; ks < 4; ks++){
            bf16x8 a = *(const bf16x8*)(xbuf + (rt*16 + cl)*136 + ks*32 + g*8);
            bf16x8 b = *(const bf16x8*)(WoB + col*128 + ks*32 + g*8);
            acc = __builtin_amdgcn_mfma_f32_16x16x32_bf16(a, b, acc, 0, 0, 0);
        }
        float bias = ob[col];
        #pragma unroll
        for (int reg = 0; reg < 4; reg++){
            int row = rt*16 + g*4 + reg;
            yf[row*132 + col] = acc[reg] + bias + xsp[(row0 + row)*128 + col];
        }
    }
    __syncthreads();
    {
        int grp = tid >> 2, sub = tid & 3;
        float s1 = 0.f, s2 = 0.f;
        const float4* yr = (const float4*)(yf + grp*132 + sub*32);
        #pragma unroll
        for (int j = 0; j < 8; j++){
            float4 v = yr[j];
            s1 += v.x + v.y + v.z + v.w;
            s2 += v.x*v.x + v.y*v.y + v.z*v.z + v.w*v.w;
        }
        s1 += __shfl_xor(s1, 1, 64); s1 += __shfl_xor(s1, 2, 64);
        s2 += __shfl_xor(s2, 1, 64); s2 += __shfl_xor(s2, 2, 64);
        if (sub == 0){
            float m = s1 * 0.0078125f;
            mrow[grp] = m;
            vrow[grp] = rsqrtf(s2 * 0.0078125f - m*m + 1e-5f);
        }
    }
    __syncthreads();
    {
        int c = tid & 127; float lw = lnw[c], lb = lnb[c];
        for (int row = tid >> 7; row < 64; row += 2)
            xt1[(row0 + row)*128 + c] = (yf[row*132 + c] - mrow[row]) * vrow[row] * lw + lb;
    }
}

// ---------------------------------------------------------------- temporal FFN1 (gelu) -> bf16 hidden (MFMA)
__global__ __launch_bounds__(256) void k_tffn1_mfma(
    const float* __restrict__ xt1, const unsigned short* __restrict__ F1B,
    const float* __restrict__ f1b, unsigned short* __restrict__ hid)
{
    __shared__ __align__(16) unsigned short xbuf[64 * 136];
    __shared__ __align__(16) unsigned short hb[64 * 264];
    int tid = threadIdx.x, wv = tid >> 6, lane = tid & 63, cl = lane & 15, g = lane >> 4;
    size_t row0 = (size_t)blockIdx.x * 64;

    const float4* x4 = (const float4*)(xt1 + row0 * 128);
    for (int i = tid; i < 2048; i += 256){
        int row = i >> 5, ch = i & 31;
        float4 v = x4[row * 32 + ch];
        ushort4 u; u.x = f2bf(v.x); u.y = f2bf(v.y); u.z = f2bf(v.z); u.w = f2bf(v.w);
        *(ushort4*)(xbuf + row * 136 + ch * 4) = u;
    }
    __syncthreads();
    for (int job = wv; job < 64; job += 4){
        int rt = job >> 4, ct = job & 15, col = ct * 16 + cl;
        f32x4 acc = {0.f, 0.f, 0.f, 0.f};
        #pragma unroll
        for (int ks = 0; ks < 4; ks++){
            bf16x8 a = *(const bf16x8*)(xbuf + (rt*16 + cl)*136 + ks*32 + g*8);
            bf16x8 b = *(const bf16x8*)(F1B + col*128 + ks*32 + g*8);
            acc = __builtin_amdgcn_mfma_f32_16x16x32_bf16(a, b, acc, 0, 0, 0);
        }
        float bias = f1b[col];
        #pragma unroll
        for (int reg = 0; reg < 4; reg++){
            int row = rt*16 + g*4 + reg;
            hb[row*264 + col] = f2bf(gelu_exact(acc[reg] + bias));
        }
    }
    __syncthreads();
    for (int i = tid; i < 2048; i += 256){
        int row = i >> 5, ch = i & 31;
        *(bf16x8*)(hid + (row0 + row)*256 + ch*8) = *(const bf16x8*)(hb + row*264 + ch*8);
    }
}

// ---------------------------------------------------------------- FFN2 + LN2 + RMSNorm + residuals -> out (MFMA)
__global__ __launch_bounds__(256) void k_final_mfma(
    const unsigned short* __restrict__ hid, const unsigned short* __restrict__ F2B,
    const float* __restrict__ f2b, const float* __restrict__ xt1,
    const float* __restrict__ ln2w, const float* __restrict__ ln2b,
    const float* __restrict__ tnw, const float* __restrict__ xsp,
    const float* __restrict__ x, float* __restrict__ out)
{
    __shared__ __align__(16) float yf[64 * 132];
    __shared__ float mrow[64], vrow[64], srow[64];
    int tid = threadIdx.x, wv = tid >> 6, lane = tid & 63, cl = lane & 15, g = lane >> 4;
    size_t row0 = (size_t)blockIdx.x * 64;

    for (int job = wv; job < 32; job += 4){
        int rt = job >> 3, ct = job & 7, col = ct * 16 + cl;
        f32x4 acc = {0.f, 0.f, 0.f, 0.f};
        #pragma unroll
        for (int ks = 0; ks < 8; ks++){
            bf16x8 a = *(const bf16x8*)(hid + (row0 + rt*16 + cl)*256 + ks*32 + g*8);
            bf16x8 b = *(const bf16x8*)(F2B + col*256 + ks*32 + g*8);
            acc = __builtin_amdgcn_mfma_f32_16x16x32_bf16(a, b, acc, 0, 0, 0);
        }
        float bias = f2b[col];
        #pragma unroll
        for (int reg = 0; reg < 4; reg++){
            int row = rt*16 + g*4 + reg;
            yf[row*132 + col] = acc[reg] + bias + xt1[(row0 + row)*128 + col];
        }
    }
    __syncthreads();
    {
        int grp = tid >> 2, sub = tid & 3;
        float s1 = 0.f, s2 = 0.f;
        const float4* yr = (const float4*)(yf + grp*132 + sub*32);
        #pragma unroll
        for (int j = 0; j < 8; j++){
            float4 v = yr[j];
            s1 += v.x + v.y + v.z + v.w;
            s2 += v.x*v.x + v.y*v.y + v.z*v.z + v.w*v.w;
        }
        s1 += __shfl_xor(s1, 1, 64); s1 += __shfl_xor(s1, 2, 64);
        s2 += __shfl_xor(s2, 1, 64); s2 += __shfl_xor(s2, 2, 64);
        if (sub == 0){
            float m = s1 * 0.0078125f;
            mrow[grp] = m;
            vrow[grp] = rsqrtf(s2 * 0.0078125f - m*m + 1e-5f);
        }
    }
    __syncthreads();
    {
        int c = tid & 127; float lw = ln2w[c], lb = ln2b[c];
        for (int row = tid >> 7; row < 64; row += 2)
            yf[row*132 + c] = (yf[row*132 + c] - mrow[row]) * vrow[row] * lw + lb;
    }
    __syncthreads();
    {
        int grp = tid >> 2, sub = tid & 3;
        float s2 = 0.f;
        const float4* yr = (const float4*)(yf + grp*132 + sub*32);
        #pragma unroll
        for (int j = 0; j < 8; j++){
            float4 v = yr[j];
            s2 += v.x*v.x + v.y*v.y + v.z*v.z + v.w*v.w;
        }
        s2 += __shfl_xor(s2, 1, 64); s2 += __shfl_xor(s2, 2, 64);
        if (sub == 0) srow[grp] = rsqrtf(s2 * 0.0078125f + 1e-6f);
    }
    __syncthreads();
    {
        int c = tid & 127; float tw = tnw[c];
        for (int row = tid >> 7; row < 64; row += 2){
            int grow = (int)row0 + row;
            int t = grow % NTT; int njq = grow / NTT; int j = njq % NJ; int n = njq / NJ;
            int xi = ((n * NTT + t) * NJ + j) * 128 + c;
            out[xi] = yf[row*132 + c] * srow[row] * tw + xsp[(size_t)grow*128 + c] + x[xi];
        }
    }
}

// ================================================================ launch
extern "C" void kernel_launch(void* const* d_in, const int* in_sizes, int n_in,
                              void* d_out, int out_size, void* d_ws, size_t ws_size,
                              hipStream_t stream) {
    (void)in_sizes; (void)n_in; (void)out_size;
    const float* x      = (const float*)d_in[0];
    const float* sc     = (const float*)d_in[1];
    const float* gcnw   = (const float*)d_in[2];
    const float* gnw    = (const float*)d_in[3];
    const float* cls    = (const float*)d_in[4];
    const float* sn1    = (const float*)d_in[5];
    const float* sn2    = (const float*)d_in[6];
    const float* s_in_w = (const float*)d_in[7];
    const float* s_in_b = (const float*)d_in[8];
    const float* s_out_w= (const float*)d_in[9];
    const float* s_out_b= (const float*)d_in[10];
    const float* s_f1w  = (const float*)d_in[11];
    const float* s_f1b  = (const float*)d_in[12];
    const float* s_f2w  = (const float*)d_in[13];
    const float* s_f2b  = (const float*)d_in[14];
    const float* t_in_w = (const float*)d_in[15];
    const float* t_in_b = (const float*)d_in[16];
    const float* t_out_w= (const float*)d_in[17];
    const float* t_out_b= (const float*)d_in[18];
    const float* t_ln1w = (const float*)d_in[19];
    const float* t_ln1b = (const float*)d_in[20];
    const float* t_ln2w = (const float*)d_in[21];
    const float* t_ln2b = (const float*)d_in[22];
    const float* t_f1w  = (const float*)d_in[23];
    const float* t_f1b  = (const float*)d_in[24];
    const float* t_f2w  = (const float*)d_in[25];
    const float* t_f2b  = (const float*)d_in[26];
    const float* tnw    = (const float*)d_in[27];

    char* ws = (char*)d_ws;
    const size_t SZ_BIG = 98304000;                 // 192000*128*4
    float* R1 = (float*)ws;                         // x_gcn -> o -> hid(bf16)
    float* R2 = (float*)(ws + SZ_BIG);              // x_sp
    float* R3 = (float*)(ws + 2 * SZ_BIG);          // delta(bf16) + xb(bf16) -> xt1
    char* p = ws + 3 * SZ_BIG;
    int*   ORD  = (int*)p;   p += 768000;
    int*   SLOT = (int*)p;   p += 768000;
    float* PH   = (float*)p; p += 245760;
    unsigned short* WM = (unsigned short*)p; p += 557056;
    if (ws_size < (size_t)(p - ws)) return;

    unsigned short* WinB  = WM;              // s_in_w  [384][128]
    unsigned short* WoutB = WM + 49152;      // s_out_w [128][128]
    unsigned short* F1B   = WM + 65536;      // s_f1w   [256][128]
    unsigned short* F2B   = WM + 98304;      // s_f2w   [128][256]
    unsigned short* WB    = WM + 131072;     // t_in_w  [384][128]
    unsigned short* WoBt  = WM + 180224;     // t_out_w [128][128]
    unsigned short* F1Bt  = WM + 196608;     // t_f1w   [256][128]
    unsigned short* F2Bt  = WM + 229376;     // t_f2w   [128][256]
    unsigned short* GWt   = WM + 262144;     // gcn_w[0]^T [128][128]

    unsigned short* DLT = (unsigned short*)R3;                          // [7680*19][128]
    unsigned short* XB  = (unsigned short*)((char*)R3 + 37355520);      // [192000][128]

    float* out0 = (float*)d_out;
    float* next_attn = out0 + 24576000;

    k_wcast<<<48, 256, 0, stream>>>(s_in_w,  WinB,  12288);
    k_wcast<<<16, 256, 0, stream>>>(s_out_w, WoutB, 4096);
    k_wcast<<<32, 256, 0, stream>>>(s_f1w,   F1B,   8192);
    k_wcast<<<32, 256, 0, stream>>>(s_f2w,   F2B,   8192);
    k_wcast<<<48, 256, 0, stream>>>(t_in_w,  WB,    12288);
    k_wcast<<<16, 256, 0, stream>>>(t_out_w, WoBt,  4096);
    k_wcast<<<32, 256, 0, stream>>>(t_f1w,   F1Bt,  8192);
    k_wcast<<<32, 256, 0, stream>>>(t_f2w,   F2Bt,  8192);
    k_tcast<<<64, 256, 0, stream>>>(gcnw, GWt);

    k_gcn_mfma<<<3000, 256, 0, stream>>>(x, GWt, gnw, R1);
    k_select<<<30, 256, 0, stream>>>(sc, ORD, SLOT, PH);
    k_spatial2<<<3840, 256, 0, stream>>>(R1, ORD, PH, cls, sn1, sn2,
                                         WinB, s_in_b, WoutB, s_out_b,
                                         F1B, s_f1b, F2B, s_f2b,
                                         DLT, next_attn);
    k_scatter2<<<24000, 256, 0, stream>>>(R1, DLT, SLOT, R2, XB);
    k_tattn_mfma<<<6400, 64, 0, stream>>>(XB, WB, t_in_b, R1);           // o -> R1
    k_tout_mfma<<<3000, 256, 0, stream>>>(R1, WoBt, t_out_b, R2,
                                          t_ln1w, t_ln1b, R3);           // xt1 -> R3
    k_tffn1_mfma<<<3000, 256, 0, stream>>>(R3, F1Bt, t_f1b, (unsigned short*)R1);
    k_final_mfma<<<3000, 256, 0, stream>>>((const unsigned short*)R1, F2Bt, t_f2b,
                                           R3, t_ln2w, t_ln2b, tnw, R2, x, out0);
}

// Round 5
// 1084.035 us; speedup vs baseline: 4.3813x; 1.1435x over previous
//
#include <hip/hip_runtime.h>
#include <hip/hip_bf16.h>
#include <math.h>

// Problem constants
#define NTR   7680      // N*T
#define NJ    25
#define NKEEP 17
#define NDRP  8
#define NL    19
#define NROW  192000    // NT*J == N*J*T
#define NTT   120
#define RSP   24        // padded rows per r in spatial block

typedef __attribute__((ext_vector_type(8))) short bf16x8;
typedef __attribute__((ext_vector_type(4))) float f32x4;

__device__ __forceinline__ float gelu_exact(float v){
    return 0.5f * v * (1.0f + erff(v * 0.70710678118654752440f));
}
__device__ __forceinline__ unsigned short f2bf(float v){
    union { float f; unsigned u; } a; a.f = v;
    unsigned r = a.u + 0x7FFF + ((a.u >> 16) & 1);   // RNE
    return (unsigned short)(r >> 16);
}
__device__ __forceinline__ float bf2f(unsigned short u){
    union { unsigned u; float f; } a; a.u = ((unsigned)u) << 16; return a.f;
}

// ---------------------------------------------------------------- weight casts
__global__ void k_wcast(const float* __restrict__ in, unsigned short* __restrict__ out, int n4){
    int i = blockIdx.x * 256 + threadIdx.x;
    if (i < n4){
        float4 v = *(const float4*)(in + i * 4);
        ushort4 o; o.x = f2bf(v.x); o.y = f2bf(v.y); o.z = f2bf(v.z); o.w = f2bf(v.w);
        *(ushort4*)(out + i * 4) = o;
    }
}
// gcn: W[c][d] -> W^T bf16 [d][c]
__global__ void k_tcast(const float* __restrict__ in, unsigned short* __restrict__ out){
    int i = blockIdx.x * 256 + threadIdx.x;   // 16384
    int d = i >> 7, c = i & 127;
    out[d * 128 + c] = f2bf(in[c * 128 + d]);
}

// ---------------------------------------------------------------- GCN + RMSNorm (MFMA)
__global__ __launch_bounds__(256) void k_gcn_mfma(
    const float* __restrict__ x, const unsigned short* __restrict__ GWt,
    const float* __restrict__ gnw, float* __restrict__ xg)
{
    __shared__ __align__(16) unsigned short xb[64 * 136];
    __shared__ __align__(16) float yf[64 * 132];
    __shared__ float rstd[64];
    int tid = threadIdx.x, wv = tid >> 6, lane = tid & 63, cl = lane & 15, g = lane >> 4;
    size_t row0 = (size_t)blockIdx.x * 64;

    const float4* x4 = (const float4*)(x + row0 * 128);
    for (int i = tid; i < 2048; i += 256){
        int row = i >> 5, ch = i & 31;
        float4 v = x4[row * 32 + ch];
        ushort4 o; o.x = f2bf(v.x); o.y = f2bf(v.y); o.z = f2bf(v.z); o.w = f2bf(v.w);
        *(ushort4*)(xb + row * 136 + ch * 4) = o;
    }
    __syncthreads();
    for (int job = wv; job < 32; job += 4){
        int rt = job >> 3, ct = job & 7, col = ct * 16 + cl;
        f32x4 acc = {0.f, 0.f, 0.f, 0.f};
        #pragma unroll
        for (int ks = 0; ks < 4; ks++){
            bf16x8 a = *(const bf16x8*)(xb + (rt*16 + cl)*136 + ks*32 + g*8);
            bf16x8 b = *(const bf16x8*)(GWt + col*128 + ks*32 + g*8);
            acc = __builtin_amdgcn_mfma_f32_16x16x32_bf16(a, b, acc, 0, 0, 0);
        }
        #pragma unroll
        for (int reg = 0; reg < 4; reg++)
            yf[(rt*16 + g*4 + reg)*132 + col] = acc[reg];
    }
    __syncthreads();
    {
        int grp = tid >> 2, sub = tid & 3;
        float ss = 0.f;
        const float4* yr = (const float4*)(yf + grp*132 + sub*32);
        #pragma unroll
        for (int j = 0; j < 8; j++){ float4 v = yr[j]; ss += v.x*v.x + v.y*v.y + v.z*v.z + v.w*v.w; }
        ss += __shfl_xor(ss, 1, 64); ss += __shfl_xor(ss, 2, 64);
        if (sub == 0) rstd[grp] = rsqrtf(ss * 0.0078125f + 1e-6f);
    }
    __syncthreads();
    {
        int c = tid & 127; float w = gnw[c];
        for (int row = tid >> 7; row < 64; row += 2)
            xg[(row0 + row)*128 + c] = yf[row*132 + c] * rstd[row] * w;
    }
}

// ---------------------------------------------------------------- per-row token selection
__global__ void k_select(const float* __restrict__ sc, int* __restrict__ order,
                         int* __restrict__ slot, float* __restrict__ ph){
    int r = blockIdx.x * blockDim.x + threadIdx.x;
    if (r >= NTR) return;
    float s[NJ]; int id[NJ];
    for (int j = 0; j < NJ; j++){ s[j] = sc[r * NJ + j]; id[j] = j; }
    for (int m = 1; m < NJ; m++){
        float sv = s[m]; int iv = id[m]; int p = m;
        while (p > 0 && s[p-1] < sv){ s[p] = s[p-1]; id[p] = id[p-1]; p--; }
        s[p] = sv; id[p] = iv;
    }
    for (int j = 0; j < NJ; j++) order[r * NJ + j] = id[j];
    for (int i = 0; i < NKEEP; i++)  slot[r * NJ + id[i]] = 1 + i;
    for (int i = NKEEP; i < NJ; i++) slot[r * NJ + id[i]] = 18;
    float m8 = s[NKEEP];
    float e[NDRP]; float sum = 0.f;
    for (int i = 0; i < NDRP; i++){ e[i] = expf(s[NKEEP + i] - m8); sum += e[i]; }
    float inv = 1.f / sum;
    for (int i = 0; i < NDRP; i++) ph[r * NDRP + i] = e[i] * inv;
}

// ---------------------------------------------------------------- spatial transformer v3: 512 thr, all-MFMA
// sm u16 layout: xs[48][136] | U1: xn[48][136] / P[8][32][40] | qk[48][264] | U2: vT[8][32][40] / ao[48][136]
__global__ __launch_bounds__(512) void k_spatial3(
    const float* __restrict__ xg, const int* __restrict__ order, const float* __restrict__ ph,
    const float* __restrict__ cls_tok, const float* __restrict__ sn1w, const float* __restrict__ sn2w,
    const unsigned short* __restrict__ WinB, const float* __restrict__ inb,
    const unsigned short* __restrict__ WoutB, const float* __restrict__ outb,
    const unsigned short* __restrict__ F1B, const float* __restrict__ f1b,
    const unsigned short* __restrict__ F2B, const float* __restrict__ f2b,
    unsigned short* __restrict__ delta, float* __restrict__ next_attn)
{
    __shared__ __align__(16) unsigned short sm[39680];
    __shared__ float rstd[48];
    __shared__ float clsp[8][20];
    __shared__ int   ord_s[2][NJ];
    __shared__ float ph_s[2][NDRP];
    unsigned short* xs = sm;             // [48][136]
    unsigned short* xn = sm + 6528;      // [48][136]
    unsigned short* Pb = sm + 6528;      // [8][32][40] overlays xn
    unsigned short* qk = sm + 16768;     // [48][264]
    unsigned short* vT = sm + 29440;     // [8][32][40]
    unsigned short* ao = sm + 29440;     // [48][136] overlays vT

    int tid = threadIdx.x;
    int r0 = blockIdx.x * 2;
    int wv = tid >> 6, lane = tid & 63, cl = lane & 15, g = lane >> 4;

    if (tid < 2*NJ)   ord_s[tid/NJ][tid%NJ] = order[(r0 + tid/NJ)*NJ + tid%NJ];
    if (tid < 2*NDRP) ph_s[tid>>3][tid&7]   = ph[(r0 + (tid>>3))*NDRP + (tid&7)];
    for (int i = tid; i < 1280; i += 512)
        *(uint4*)(vT + i*8) = make_uint4(0,0,0,0);   // zero U2 (pad keys must be 0)
    __syncthreads();

    // ---- build x_slow (vectorized: 32 lanes/row, 16 rows in parallel) ----
    {
        int ln = tid & 31;
        for (int j = tid >> 5; j < 48; j += 16){
            int rr = j / RSP, t = j - rr * RSP;
            const float* xgr = xg + (size_t)(r0 + rr) * NJ * 128;
            float4 v;
            if (t == 0)          v = *(const float4*)(cls_tok + ln*4);
            else if (t <= NKEEP) v = *(const float4*)(xgr + ord_s[rr][t-1]*128 + ln*4);
            else if (t == 18){
                v = make_float4(0.f,0.f,0.f,0.f);
                for (int i = 0; i < NDRP; i++){
                    float4 u = *(const float4*)(xgr + ord_s[rr][NKEEP+i]*128 + ln*4);
                    float w = ph_s[rr][i];
                    v.x = fmaf(u.x,w,v.x); v.y = fmaf(u.y,w,v.y);
                    v.z = fmaf(u.z,w,v.z); v.w = fmaf(u.w,w,v.w);
                }
            } else v = make_float4(0.f,0.f,0.f,0.f);
            ushort4 o4; o4.x=f2bf(v.x); o4.y=f2bf(v.y); o4.z=f2bf(v.z); o4.w=f2bf(v.w);
            *(ushort4*)(xs + j*136 + ln*4) = o4;
        }
    }
    __syncthreads();

    // ---- rmsnorm1 ----
    {
        int grp = tid >> 2, sub = tid & 3;
        if (grp < 48){
            float ss = 0.f;
            #pragma unroll
            for (int j = 0; j < 4; j++){
                bf16x8 v = *(const bf16x8*)(xs + grp*136 + sub*32 + j*8);
                #pragma unroll
                for (int e = 0; e < 8; e++){ float f = bf2f((unsigned short)v[e]); ss = fmaf(f, f, ss); }
            }
            ss += __shfl_xor(ss, 1, 64); ss += __shfl_xor(ss, 2, 64);
            if (sub == 0) rstd[grp] = rsqrtf(ss * 0.0078125f + 1e-6f);
        }
    }
    __syncthreads();
    {
        int c = tid & 127; float w = sn1w[c];
        for (int row = tid >> 7; row < 48; row += 4)
            xn[row*136 + c] = f2bf(bf2f(xs[row*136 + c]) * rstd[row] * w);
    }
    __syncthreads();

    // ---- qkv GEMM: q (scaled) + k -> qk, v -> vT ----
    for (int job = wv; job < 72; job += 8){
        int rt = job / 24, ct = job - rt*24, col = ct*16 + cl;
        f32x4 acc = {0.f, 0.f, 0.f, 0.f};
        #pragma unroll
        for (int ks = 0; ks < 4; ks++){
            bf16x8 a = *(const bf16x8*)(xn + (rt*16 + cl)*136 + ks*32 + g*8);
            bf16x8 b = *(const bf16x8*)(WinB + col*128 + ks*32 + g*8);
            acc = __builtin_amdgcn_mfma_f32_16x16x32_bf16(a, b, acc, 0, 0, 0);
        }
        float bias = inb[col];
        if (col < 128){
            #pragma unroll
            for (int reg = 0; reg < 4; reg++){
                int row = rt*16 + g*4 + reg;
                qk[row*264 + col] = f2bf((acc[reg] + bias) * 0.17677669529663687f);
            }
        } else if (col < 256){
            #pragma unroll
            for (int reg = 0; reg < 4; reg++){
                int row = rt*16 + g*4 + reg;
                qk[row*264 + col] = f2bf(acc[reg] + bias);
            }
        } else {
            int h = (col - 256) >> 5, d = (col - 256) & 31;
            #pragma unroll
            for (int reg = 0; reg < 4; reg++){
                int row = rt*16 + g*4 + reg;
                int rr = row >= RSP; int key = row - rr*RSP;
                vT[(rr*4 + h)*1280 + d*40 + key] = f2bf(acc[reg] + bias);
            }
        }
    }
    __syncthreads();

    // ---- attention: 1 (rr,h) pair per wave, MFMA QK^T + reg softmax + MFMA PV ----
    {
        int qh = wv;
        int rr = qh >> 2, h = qh & 3;
        bf16x8 aq[2];
        #pragma unroll
        for (int qt = 0; qt < 2; qt++)
            aq[qt] = *(const bf16x8*)(qk + (rr*RSP + qt*16 + cl)*264 + h*32 + g*8);
        f32x4 lg[2][2];
        #pragma unroll
        for (int kt = 0; kt < 2; kt++){
            bf16x8 bk = *(const bf16x8*)(qk + (rr*RSP + kt*16 + cl)*264 + 128 + h*32 + g*8);
            f32x4 z = {0.f, 0.f, 0.f, 0.f};
            lg[0][kt] = __builtin_amdgcn_mfma_f32_16x16x32_bf16(aq[0], bk, z, 0, 0, 0);
            lg[1][kt] = __builtin_amdgcn_mfma_f32_16x16x32_bf16(aq[1], bk, z, 0, 0, 0);
        }
        #pragma unroll
        for (int qt = 0; qt < 2; qt++){
            #pragma unroll
            for (int reg = 0; reg < 4; reg++){
                float l0 = lg[qt][0][reg];
                float l1 = (cl >= 3) ? -1e30f : lg[qt][1][reg];
                float m = fmaxf(l0, l1);
                m = fmaxf(m, __shfl_xor(m, 1, 64));
                m = fmaxf(m, __shfl_xor(m, 2, 64));
                m = fmaxf(m, __shfl_xor(m, 4, 64));
                m = fmaxf(m, __shfl_xor(m, 8, 64));
                float e0 = __expf(l0 - m), e1 = __expf(l1 - m);
                float ssum = e0 + e1;
                ssum += __shfl_xor(ssum, 1, 64); ssum += __shfl_xor(ssum, 2, 64);
                ssum += __shfl_xor(ssum, 4, 64); ssum += __shfl_xor(ssum, 8, 64);
                float inv = 1.f / ssum;
                e0 *= inv; e1 *= inv;
                int q = qt*16 + g*4 + reg;
                Pb[qh*1280 + q*40 + cl]      = f2bf(e0);
                Pb[qh*1280 + q*40 + 16 + cl] = f2bf(e1);
                if (qt == 0 && g == 0 && reg == 0){
                    clsp[qh][cl] = e0;
                    if (cl < 4) clsp[qh][16 + cl] = e1;
                }
            }
        }
        __syncthreads();    // P visible
        bf16x8 ap[2];
        #pragma unroll
        for (int qt = 0; qt < 2; qt++)
            ap[qt] = *(const bf16x8*)(Pb + qh*1280 + (qt*16 + cl)*40 + g*8);
        #pragma unroll
        for (int dt = 0; dt < 2; dt++){
            bf16x8 bv = *(const bf16x8*)(vT + qh*1280 + (dt*16 + cl)*40 + g*8);
            #pragma unroll
            for (int qt = 0; qt < 2; qt++){
                f32x4 z = {0.f, 0.f, 0.f, 0.f};
                f32x4 oa = __builtin_amdgcn_mfma_f32_16x16x32_bf16(ap[qt], bv, z, 0, 0, 0);
                #pragma unroll
                for (int reg = 0; reg < 4; reg++){
                    int q = qt*16 + g*4 + reg;
                    if (q < 19)
                        qk[(rr*RSP + q)*264 + h*32 + dt*16 + cl] = f2bf(oa[reg]);
                    else if (q < RSP)
                        qk[(rr*RSP + q)*264 + h*32 + dt*16 + cl] = 0;
                }
            }
        }
        __syncthreads();
    }

    // ---- next_attn (f32 probs from clsp) ----
    if (tid < 36){
        int rr2 = tid / 18, t = tid - rr2*18;
        float v = 0.25f * (clsp[rr2*4+0][1+t] + clsp[rr2*4+1][1+t] +
                           clsp[rr2*4+2][1+t] + clsp[rr2*4+3][1+t]);
        int r = r0 + rr2;
        if (t < NKEEP) next_attn[r*NJ + ord_s[rr2][t]] = v;
        else { for (int i = 0; i < NDRP; i++) next_attn[r*NJ + ord_s[rr2][NKEEP+i]] = v; }
    }

    // ---- out-proj: attn_out -> ao, x_msa -> xs ----
    for (int job = wv; job < 24; job += 8){
        int rt = job >> 3, ct = job & 7, col = ct*16 + cl;
        f32x4 acc = {0.f, 0.f, 0.f, 0.f};
        #pragma unroll
        for (int ks = 0; ks < 4; ks++){
            bf16x8 a = *(const bf16x8*)(qk + (rt*16 + cl)*264 + ks*32 + g*8);
            bf16x8 b = *(const bf16x8*)(WoutB + col*128 + ks*32 + g*8);
            acc = __builtin_amdgcn_mfma_f32_16x16x32_bf16(a, b, acc, 0, 0, 0);
        }
        float bias = outb[col];
        #pragma unroll
        for (int reg = 0; reg < 4; reg++){
            int row = rt*16 + g*4 + reg;
            float v = acc[reg] + bias;
            ao[row*136 + col] = f2bf(v);
            xs[row*136 + col] = f2bf(bf2f(xs[row*136 + col]) + v);
        }
    }
    __syncthreads();

    // ---- rmsnorm2 ----
    {
        int grp = tid >> 2, sub = tid & 3;
        if (grp < 48){
            float ss = 0.f;
            #pragma unroll
            for (int j = 0; j < 4; j++){
                bf16x8 v = *(const bf16x8*)(xs + grp*136 + sub*32 + j*8);
                #pragma unroll
                for (int e = 0; e < 8; e++){ float f = bf2f((unsigned short)v[e]); ss = fmaf(f, f, ss); }
            }
            ss += __shfl_xor(ss, 1, 64); ss += __shfl_xor(ss, 2, 64);
            if (sub == 0) rstd[grp] = rsqrtf(ss * 0.0078125f + 1e-6f);
        }
    }
    __syncthreads();
    {
        int c = tid & 127; float w = sn2w[c];
        for (int row = tid >> 7; row < 48; row += 4)
            xn[row*136 + c] = f2bf(bf2f(xs[row*136 + c]) * rstd[row] * w);
    }
    __syncthreads();

    // ---- ffn1 + gelu -> qk cols 0..255 ----
    for (int job = wv; job < 48; job += 8){
        int rt = job >> 4, ct = job & 15, col = ct*16 + cl;
        f32x4 acc = {0.f, 0.f, 0.f, 0.f};
        #pragma unroll
        for (int ks = 0; ks < 4; ks++){
            bf16x8 a = *(const bf16x8*)(xn + (rt*16 + cl)*136 + ks*32 + g*8);
            bf16x8 b = *(const bf16x8*)(F1B + col*128 + ks*32 + g*8);
            acc = __builtin_amdgcn_mfma_f32_16x16x32_bf16(a, b, acc, 0, 0, 0);
        }
        float bias = f1b[col];
        #pragma unroll
        for (int reg = 0; reg < 4; reg++){
            int row = rt*16 + g*4 + reg;
            qk[row*264 + col] = f2bf(gelu_exact(acc[reg] + bias));
        }
    }
    __syncthreads();

    // ---- ffn2 + delta ----
    for (int job = wv; job < 24; job += 8){
        int rt = job >> 3, ct = job & 7, col = ct*16 + cl;
        f32x4 acc = {0.f, 0.f, 0.f, 0.f};
        #pragma unroll
        for (int ks = 0; ks < 8; ks++){
            bf16x8 a = *(const bf16x8*)(qk + (rt*16 + cl)*264 + ks*32 + g*8);
            bf16x8 b = *(const bf16x8*)(F2B + col*256 + ks*32 + g*8);
            acc = __builtin_amdgcn_mfma_f32_16x16x32_bf16(a, b, acc, 0, 0, 0);
        }
        float bias = f2b[col];
        #pragma unroll
        for (int reg = 0; reg < 4; reg++){
            int row = rt*16 + g*4 + reg;
            int rr = row >= RSP; int tok = row - rr*RSP;
            if (tok < 19){
                float dv = acc[reg] + bias + bf2f(ao[row*136 + col]);
                delta[((size_t)(r0 + rr)*19 + tok)*128 + col] = f2bf(dv);
            }
        }
    }
}

// ---------------------------------------------------------------- scatter + bf16 cast fused
__global__ void k_scatter2(const float* __restrict__ xg, const unsigned short* __restrict__ delta,
                           const int* __restrict__ slot, float* __restrict__ xsp,
                           unsigned short* __restrict__ xb){
    int i = blockIdx.x * 256 + threadIdx.x;   // 6,144,000 quads
    int e = i * 4;
    int c = e & 127; int rem = e >> 7;
    int t = rem % NTT; int nj = rem / NTT; int j = nj % NJ; int n = nj / NJ;
    int r = n * NTT + t;
    int sl = slot[r * NJ + j];
    float4 xv = *(const float4*)(xg + ((size_t)r * NJ + j) * 128 + c);
    ushort4 dv = *(const ushort4*)(delta + ((size_t)r * 19 + sl) * 128 + c);
    float4 o;
    o.x = 2.f * xv.x + bf2f(dv.x);
    o.y = 2.f * xv.y + bf2f(dv.y);
    o.z = 2.f * xv.z + bf2f(dv.z);
    o.w = 2.f * xv.w + bf2f(dv.w);
    *(float4*)(xsp + e) = o;
    ushort4 ob; ob.x = f2bf(o.x); ob.y = f2bf(o.y); ob.z = f2bf(o.z); ob.w = f2bf(o.w);
    *(ushort4*)(xb + e) = ob;
}

// ---------------------------------------------------------------- temporal attention v2: 4 waves per (nj, head)
__global__ __launch_bounds__(256) void k_tattn2(
    const unsigned short* __restrict__ xb, const unsigned short* __restrict__ Wb,
    const float* __restrict__ inb, float* __restrict__ o)
{
    // LDS u16: q[120][40] | k[120][40] | vT[32][136] | P[4][16][136] = 45,312 B
    __shared__ __align__(16) unsigned short smem[22656];
    unsigned short* q_s = smem;
    unsigned short* k_s = smem + 4800;
    unsigned short* vT  = smem + 9600;
    unsigned short* P_s = smem + 13952;

    int tid = threadIdx.x;
    int l = tid & 63, cl = l & 15, g = l >> 4, wv = tid >> 6;
    int nj = blockIdx.x >> 2;
    int h  = blockIdx.x & 3;

    vT[(tid >> 3) * 136 + 120 + (tid & 7)] = 0;   // zero pad key cols (256 entries)

    const unsigned short* xrow = xb + (size_t)nj * (NTT * 128);
    const float scale = 0.17677669529663687f;

    bf16x8 bfr[6][4];
    float bias[6];
    #pragma unroll
    for (int pc = 0; pc < 6; ++pc){
        int p = pc >> 1, s = pc & 1;
        int col = p * 128 + h * 32 + s * 16 + cl;
        bias[pc] = inb[col];
        #pragma unroll
        for (int ks = 0; ks < 4; ++ks)
            bfr[pc][ks] = *(const bf16x8*)(Wb + col * 128 + ks * 32 + g * 8);
    }

    for (int mt = wv; mt < 8; mt += 4){
        bf16x8 af[4];
        #pragma unroll
        for (int ks = 0; ks < 4; ++ks)
            af[ks] = *(const bf16x8*)(xrow + (mt * 16 + cl) * 128 + ks * 32 + g * 8);
        #pragma unroll
        for (int pc = 0; pc < 6; ++pc){
            f32x4 acc = {0.f, 0.f, 0.f, 0.f};
            #pragma unroll
            for (int ks = 0; ks < 4; ++ks)
                acc = __builtin_amdgcn_mfma_f32_16x16x32_bf16(af[ks], bfr[pc][ks], acc, 0, 0, 0);
            int p = pc >> 1, s = pc & 1;
            int d = s * 16 + cl;
            #pragma unroll
            for (int reg = 0; reg < 4; ++reg){
                int t = mt * 16 + g * 4 + reg;
                if (t < NTT){
                    float v = acc[reg] + bias[pc];
                    if (p == 0)      q_s[t * 40 + d] = f2bf(v * scale);
                    else if (p == 1) k_s[t * 40 + d] = f2bf(v);
                    else             vT[d * 136 + t] = f2bf(v);
                }
            }
        }
    }
    __syncthreads();

    for (int s = 0; s < 2; ++s){
        int mt = wv + s * 4;
        bf16x8 aq = *(const bf16x8*)(q_s + (mt * 16 + cl) * 40 + g * 8);
        f32x4 lg[8];
        #pragma unroll
        for (int jt = 0; jt < 8; ++jt){
            bf16x8 bk = *(const bf16x8*)(k_s + (jt * 16 + cl) * 40 + g * 8);
            f32x4 z = {0.f, 0.f, 0.f, 0.f};
            lg[jt] = __builtin_amdgcn_mfma_f32_16x16x32_bf16(aq, bk, z, 0, 0, 0);
        }
        if (cl >= 8){ lg[7][0] = -1e30f; lg[7][1] = -1e30f; lg[7][2] = -1e30f; lg[7][3] = -1e30f; }

        float inv[4];
        #pragma unroll
        for (int reg = 0; reg < 4; ++reg){
            float m = lg[0][reg];
            #pragma unroll
            for (int jt = 1; jt < 8; ++jt) m = fmaxf(m, lg[jt][reg]);
            m = fmaxf(m, __shfl_xor(m, 1, 64));
            m = fmaxf(m, __shfl_xor(m, 2, 64));
            m = fmaxf(m, __shfl_xor(m, 4, 64));
            m = fmaxf(m, __shfl_xor(m, 8, 64));
            float sum = 0.f;
            #pragma unroll
            for (int jt = 0; jt < 8; ++jt){ float e = __expf(lg[jt][reg] - m); lg[jt][reg] = e; sum += e; }
            sum += __shfl_xor(sum, 1, 64); sum += __shfl_xor(sum, 2, 64);
            sum += __shfl_xor(sum, 4, 64); sum += __shfl_xor(sum, 8, 64);
            inv[reg] = 1.f / sum;
        }

        unsigned short* Pw = P_s + wv * 2176;
        #pragma unroll
        for (int jt = 0; jt < 8; ++jt){
            #pragma unroll
            for (int reg = 0; reg < 4; ++reg)
                Pw[(g * 4 + reg) * 136 + jt * 16 + cl] = f2bf(lg[jt][reg] * inv[reg]);
        }
        __syncthreads();   // conservative intra-wave fence (all waves aligned)

        bf16x8 ap[4];
        #pragma unroll
        for (int ks = 0; ks < 4; ++ks)
            ap[ks] = *(const bf16x8*)(Pw + cl * 136 + ks * 32 + g * 8);
        #pragma unroll
        for (int nt = 0; nt < 2; ++nt){
            f32x4 oacc = {0.f, 0.f, 0.f, 0.f};
            #pragma unroll
            for (int ks = 0; ks < 4; ++ks){
                bf16x8 bv = *(const bf16x8*)(vT + (nt * 16 + cl) * 136 + ks * 32 + g * 8);
                oacc = __builtin_amdgcn_mfma_f32_16x16x32_bf16(ap[ks], bv, oacc, 0, 0, 0);
            }
            #pragma unroll
            for (int reg = 0; reg < 4; ++reg){
                int t = mt * 16 + g * 4 + reg;
                if (t < NTT)
                    o[((size_t)nj * NTT + t) * 128 + h * 32 + nt * 16 + cl] = oacc[reg];
            }
        }
        __syncthreads();   // WAR: P region reuse in next s
    }
}

// ---------------------------------------------------------------- temporal out-proj + residual + LN1 (MFMA)
__global__ __launch_bounds__(256) void k_tout_mfma(
    const float* __restrict__ o, const unsigned short* __restrict__ WoB,
    const float* __restrict__ ob, const float* __restrict__ xsp,
    const float* __restrict__ lnw, const float* __restrict__ lnb,
    float* __restrict__ xt1)
{
    __shared__ __align__(16) unsigned short xbuf[64 * 136];
    __shared__ __align__(16) float yf[64 * 132];
    __shared__ float mrow[64], vrow[64];
    int tid = threadIdx.x, wv = tid >> 6, lane = tid & 63, cl = lane & 15, g = lane >> 4;
    size_t row0 = (size_t)blockIdx.x * 64;

    const float4* x4 = (const float4*)(o + row0 * 128);
    for (int i = tid; i < 2048; i += 256){
        int row = i >> 5, ch = i & 31;
        float4 v = x4[row * 32 + ch];
        ushort4 u; u.x = f2bf(v.x); u.y = f2bf(v.y); u.z = f2bf(v.z); u.w = f2bf(v.w);
        *(ushort4*)(xbuf + row * 136 + ch * 4) = u;
    }
    __syncthreads();
    for (int job = wv; job < 32; job += 4){
        int rt = job >> 3, ct = job & 7, col = ct * 16 + cl;
        f32x4 acc = {0.f, 0.f, 0.f, 0.f};
        #pragma unroll
        for (int ks = 0; ks < 4; ks++){
            bf16x8 a = *(const bf16x8*)(xbuf + (rt*16 + cl)*136 + ks*32 + g*8);
            bf16x8 b = *(const bf16x8*)(WoB + col*128 + ks*32 + g*8);
            acc = __builtin_amdgcn_mfma_f32_16x16x32_bf16(a, b, acc, 0, 0, 0);
        }
        float bias = ob[col];
        #pragma unroll
        for (int reg = 0; reg < 4; reg++){
            int row = rt*16 + g*4 + reg;
            yf[row*132 + col] = acc[reg] + bias + xsp[(row0 + row)*128 + col];
        }
    }
    __syncthreads();
    {
        int grp = tid >> 2, sub = tid & 3;
        float s1 = 0.f, s2 = 0.f;
        const float4* yr = (const float4*)(yf + grp*132 + sub*32);
        #pragma unroll
        for (int j = 0; j < 8; j++){
            float4 v = yr[j];
            s1 += v.x + v.y + v.z + v.w;
            s2 += v.x*v.x + v.y*v.y + v.z*v.z + v.w*v.w;
        }
        s1 += __shfl_xor(s1, 1, 64); s1 += __shfl_xor(s1, 2, 64);
        s2 += __shfl_xor(s2, 1, 64); s2 += __shfl_xor(s2, 2, 64);
        if (sub == 0){
            float m = s1 * 0.0078125f;
            mrow[grp] = m;
            vrow[grp] = rsqrtf(s2 * 0.0078125f - m*m + 1e-5f);
        }
    }
    __syncthreads();
    {
        int c = tid & 127; float lw = lnw[c], lb = lnb[c];
        for (int row = tid >> 7; row < 64; row += 2)
            xt1[(row0 + row)*128 + c] = (yf[row*132 + c] - mrow[row]) * vrow[row] * lw + lb;
    }
}

// ---------------------------------------------------------------- temporal FFN1 (gelu) -> bf16 hidden (MFMA)
__global__ __launch_bounds__(256) void k_tffn1_mfma(
    const float* __restrict__ xt1, const unsigned short* __restrict__ F1B,
    const float* __restrict__ f1b, unsigned short* __restrict__ hid)
{
    __shared__ __align__(16) unsigned short xbuf[64 * 136];
    __shared__ __align__(16) unsigned short hb[64 * 264];
    int tid = threadIdx.x, wv = tid >> 6, lane = tid & 63, cl = lane & 15, g = lane >> 4;
    size_t row0 = (size_t)blockIdx.x * 64;

    const float4* x4 = (const float4*)(xt1 + row0 * 128);
    for (int i = tid; i < 2048; i += 256){
        int row = i >> 5, ch = i & 31;
        float4 v = x4[row * 32 + ch];
        ushort4 u; u.x = f2bf(v.x); u.y = f2bf(v.y); u.z = f2bf(v.z); u.w = f2bf(v.w);
        *(ushort4*)(xbuf + row * 136 + ch * 4) = u;
    }
    __syncthreads();
    for (int job = wv; job < 64; job += 4){
        int rt = job >> 4, ct = job & 15, col = ct * 16 + cl;
        f32x4 acc = {0.f, 0.f, 0.f, 0.f};
        #pragma unroll
        for (int ks = 0; ks < 4; ks++){
            bf16x8 a = *(const bf16x8*)(xbuf + (rt*16 + cl)*136 + ks*32 + g*8);
            bf16x8 b = *(const bf16x8*)(F1B + col*128 + ks*32 + g*8);
            acc = __builtin_amdgcn_mfma_f32_16x16x32_bf16(a, b, acc, 0, 0, 0);
        }
        float bias = f1b[col];
        #pragma unroll
        for (int reg = 0; reg < 4; reg++){
            int row = rt*16 + g*4 + reg;
            hb[row*264 + col] = f2bf(gelu_exact(acc[reg] + bias));
        }
    }
    __syncthreads();
    for (int i = tid; i < 2048; i += 256){
        int row = i >> 5, ch = i & 31;
        *(bf16x8*)(hid + (row0 + row)*256 + ch*8) = *(const bf16x8*)(hb + row*264 + ch*8);
    }
}

// ---------------------------------------------------------------- FFN2 + LN2 + RMSNorm + residuals -> out (MFMA)
__global__ __launch_bounds__(256) void k_final_mfma(
    const unsigned short* __restrict__ hid, const unsigned short* __restrict__ F2B,
    const float* __restrict__ f2b, const float* __restrict__ xt1,
    const float* __restrict__ ln2w, const float* __restrict__ ln2b,
    const float* __restrict__ tnw, const float* __restrict__ xsp,
    const float* __restrict__ x, float* __restrict__ out)
{
    __shared__ __align__(16) float yf[64 * 132];
    __shared__ float mrow[64], vrow[64], srow[64];
    int tid = threadIdx.x, wv = tid >> 6, lane = tid & 63, cl = lane & 15, g = lane >> 4;
    size_t row0 = (size_t)blockIdx.x * 64;

    for (int job = wv; job < 32; job += 4){
        int rt = job >> 3, ct = job & 7, col = ct * 16 + cl;
        f32x4 acc = {0.f, 0.f, 0.f, 0.f};
        #pragma unroll
        for (int ks = 0; ks < 8; ks++){
            bf16x8 a = *(const bf16x8*)(hid + (row0 + rt*16 + cl)*256 + ks*32 + g*8);
            bf16x8 b = *(const bf16x8*)(F2B + col*256 + ks*32 + g*8);
            acc = __builtin_amdgcn_mfma_f32_16x16x32_bf16(a, b, acc, 0, 0, 0);
        }
        float bias = f2b[col];
        #pragma unroll
        for (int reg = 0; reg < 4; reg++){
            int row = rt*16 + g*4 + reg;
            yf[row*132 + col] = acc[reg] + bias + xt1[(row0 + row)*128 + col];
        }
    }
    __syncthreads();
    {
        int grp = tid >> 2, sub = tid & 3;
        float s1 = 0.f, s2 = 0.f;
        const float4* yr = (const float4*)(yf + grp*132 + sub*32);
        #pragma unroll
        for (int j = 0; j < 8; j++){
            float4 v = yr[j];
            s1 += v.x + v.y + v.z + v.w;
            s2 += v.x*v.x + v.y*v.y + v.z*v.z + v.w*v.w;
        }
        s1 += __shfl_xor(s1, 1, 64); s1 += __shfl_xor(s1, 2, 64);
        s2 += __shfl_xor(s2, 1, 64); s2 += __shfl_xor(s2, 2, 64);
        if (sub == 0){
            float m = s1 * 0.0078125f;
            mrow[grp] = m;
            vrow[grp] = rsqrtf(s2 * 0.0078125f - m*m + 1e-5f);
        }
    }
    __syncthreads();
    {
        int c = tid & 127; float lw = ln2w[c], lb = ln2b[c];
        for (int row = tid >> 7; row < 64; row += 2)
            yf[row*132 + c] = (yf[row*132 + c] - mrow[row]) * vrow[row] * lw + lb;
    }
    __syncthreads();
    {
        int grp = tid >> 2, sub = tid & 3;
        float s2 = 0.f;
        const float4* yr = (const float4*)(yf + grp*132 + sub*32);
        #pragma unroll
        for (int j = 0; j < 8; j++){
            float4 v = yr[j];
            s2 += v.x*v.x + v.y*v.y + v.z*v.z + v.w*v.w;
        }
        s2 += __shfl_xor(s2, 1, 64); s2 += __shfl_xor(s2, 2, 64);
        if (sub == 0) srow[grp] = rsqrtf(s2 * 0.0078125f + 1e-6f);
    }
    __syncthreads();
    {
        int c = tid & 127; float tw = tnw[c];
        for (int row = tid >> 7; row < 64; row += 2){
            int grow = (int)row0 + row;
            int t = grow % NTT; int njq = grow / NTT; int j = njq % NJ; int n = njq / NJ;
            int xi = ((n * NTT + t) * NJ + j) * 128 + c;
            out[xi] = yf[row*132 + c] * srow[row] * tw + xsp[(size_t)grow*128 + c] + x[xi];
        }
    }
}

// ================================================================ launch
extern "C" void kernel_launch(void* const* d_in, const int* in_sizes, int n_in,
                              void* d_out, int out_size, void* d_ws, size_t ws_size,
                              hipStream_t stream) {
    (void)in_sizes; (void)n_in; (void)out_size;
    const float* x      = (const float*)d_in[0];
    const float* sc     = (const float*)d_in[1];
    const float* gcnw   = (const float*)d_in[2];
    const float* gnw    = (const float*)d_in[3];
    const float* cls    = (const float*)d_in[4];
    const float* sn1    = (const float*)d_in[5];
    const float* sn2    = (const float*)d_in[6];
    const float* s_in_w = (const float*)d_in[7];
    const float* s_in_b = (const float*)d_in[8];
    const float* s_out_w= (const float*)d_in[9];
    const float* s_out_b= (const float*)d_in[10];
    const float* s_f1w  = (const float*)d_in[11];
    const float* s_f1b  = (const float*)d_in[12];
    const float* s_f2w  = (const float*)d_in[13];
    const float* s_f2b  = (const float*)d_in[14];
    const float* t_in_w = (const float*)d_in[15];
    const float* t_in_b = (const float*)d_in[16];
    const float* t_out_w= (const float*)d_in[17];
    const float* t_out_b= (const float*)d_in[18];
    const float* t_ln1w = (const float*)d_in[19];
    const float* t_ln1b = (const float*)d_in[20];
    const float* t_ln2w = (const float*)d_in[21];
    const float* t_ln2b = (const float*)d_in[22];
    const float* t_f1w  = (const float*)d_in[23];
    const float* t_f1b  = (const float*)d_in[24];
    const float* t_f2w  = (const float*)d_in[25];
    const float* t_f2b  = (const float*)d_in[26];
    const float* tnw    = (const float*)d_in[27];

    char* ws = (char*)d_ws;
    const size_t SZ_BIG = 98304000;                 // 192000*128*4
    float* R1 = (float*)ws;                         // x_gcn -> o -> hid(bf16)
    float* R2 = (float*)(ws + SZ_BIG);              // x_sp
    float* R3 = (float*)(ws + 2 * SZ_BIG);          // delta(bf16) + xb(bf16) -> xt1
    char* p = ws + 3 * SZ_BIG;
    int*   ORD  = (int*)p;   p += 768000;
    int*   SLOT = (int*)p;   p += 768000;
    float* PH   = (float*)p; p += 245760;
    unsigned short* WM = (unsigned short*)p; p += 557056;
    if (ws_size < (size_t)(p - ws)) return;

    unsigned short* WinB  = WM;              // s_in_w  [384][128]
    unsigned short* WoutB = WM + 49152;      // s_out_w [128][128]
    unsigned short* F1B   = WM + 65536;      // s_f1w   [256][128]
    unsigned short* F2B   = WM + 98304;      // s_f2w   [128][256]
    unsigned short* WB    = WM + 131072;     // t_in_w  [384][128]
    unsigned short* WoBt  = WM + 180224;     // t_out_w [128][128]
    unsigned short* F1Bt  = WM + 196608;     // t_f1w   [256][128]
    unsigned short* F2Bt  = WM + 229376;     // t_f2w   [128][256]
    unsigned short* GWt   = WM + 262144;     // gcn_w[0]^T [128][128]

    unsigned short* DLT = (unsigned short*)R3;                          // [7680*19][128]
    unsigned short* XB  = (unsigned short*)((char*)R3 + 37355520);      // [192000][128]

    float* out0 = (float*)d_out;
    float* next_attn = out0 + 24576000;

    k_wcast<<<48, 256, 0, stream>>>(s_in_w,  WinB,  12288);
    k_wcast<<<16, 256, 0, stream>>>(s_out_w, WoutB, 4096);
    k_wcast<<<32, 256, 0, stream>>>(s_f1w,   F1B,   8192);
    k_wcast<<<32, 256, 0, stream>>>(s_f2w,   F2B,   8192);
    k_wcast<<<48, 256, 0, stream>>>(t_in_w,  WB,    12288);
    k_wcast<<<16, 256, 0, stream>>>(t_out_w, WoBt,  4096);
    k_wcast<<<32, 256, 0, stream>>>(t_f1w,   F1Bt,  8192);
    k_wcast<<<32, 256, 0, stream>>>(t_f2w,   F2Bt,  8192);
    k_tcast<<<64, 256, 0, stream>>>(gcnw, GWt);

    k_gcn_mfma<<<3000, 256, 0, stream>>>(x, GWt, gnw, R1);
    k_select<<<30, 256, 0, stream>>>(sc, ORD, SLOT, PH);
    k_spatial3<<<3840, 512, 0, stream>>>(R1, ORD, PH, cls, sn1, sn2,
                                         WinB, s_in_b, WoutB, s_out_b,
                                         F1B, s_f1b, F2B, s_f2b,
                                         DLT, next_attn);
    k_scatter2<<<24000, 256, 0, stream>>>(R1, DLT, SLOT, R2, XB);
    k_tattn2<<<6400, 256, 0, stream>>>(XB, WB, t_in_b, R1);              // o -> R1
    k_tout_mfma<<<3000, 256, 0, stream>>>(R1, WoBt, t_out_b, R2,
                                          t_ln1w, t_ln1b, R3);           // xt1 -> R3
    k_tffn1_mfma<<<3000, 256, 0, stream>>>(R3, F1Bt, t_f1b, (unsigned short*)R1);
    k_final_mfma<<<3000, 256, 0, stream>>>((const unsigned short*)R1, F2Bt, t_f2b,
                                           R3, t_ln2w, t_ln2b, tnw, R2, x, out0);
}